// Round 6
// baseline (806.418 us; speedup 1.0000x reference)
//
#include <hip/hip_runtime.h>
#include <hip/hip_bf16.h>
#include <stdint.h>
#include <math.h>

#define NT_ 65536
#define BGRAPH 128
#define NNODE 512
#define DIM 128
#define HID 128
#define H2 256
#define EDGES 1048576
#define KSEL 256
#define OUTC 10

// ---------------- CSR build ----------------
__global__ void k_count(const int* __restrict__ dst, int* __restrict__ counts) {
    int e = blockIdx.x * blockDim.x + threadIdx.x;
    if (e < EDGES) atomicAdd(&counts[dst[e]], 1);
}

__global__ __launch_bounds__(1024) void k_scan(const int* __restrict__ counts,
                                               int* __restrict__ row_start,
                                               int* __restrict__ cursor) {
    __shared__ int part[1024];
    int t = threadIdx.x;
    int base = t * 64;
    int s = 0;
    #pragma unroll
    for (int i = 0; i < 64; ++i) s += counts[base + i];
    part[t] = s;
    __syncthreads();
    for (int off = 1; off < 1024; off <<= 1) {
        int v = (t >= off) ? part[t - off] : 0;
        __syncthreads();
        part[t] += v;
        __syncthreads();
    }
    int run = part[t] - s;   // exclusive prefix of this 64-chunk
    for (int i = 0; i < 64; ++i) {
        row_start[base + i] = run;
        cursor[base + i] = run;
        run += counts[base + i];
    }
    if (t == 1023) row_start[NT_] = part[1023];
}

// store EDGE IDS (order within row nondeterministic; sorted next)
__global__ void k_fill(const int* __restrict__ dst,
                       int* __restrict__ cursor, int* __restrict__ csr) {
    int e = blockIdx.x * blockDim.x + threadIdx.x;
    if (e < EDGES) {
        int d = dst[e];
        int pos = atomicAdd(&cursor[d], 1);
        csr[pos] = e;
    }
}

// sort each row's edge-ids ascending (restore edge order), then map eid->src
__global__ void k_sortrows(const int* __restrict__ src, const int* __restrict__ row_start,
                           int* __restrict__ csr) {
    int n = blockIdx.x * blockDim.x + threadIdx.x;
    if (n >= NT_) return;
    int beg = row_start[n], end = row_start[n + 1];
    for (int i = beg + 1; i < end; ++i) {
        int key = csr[i];
        int j = i - 1;
        while (j >= beg && csr[j] > key) { csr[j + 1] = csr[j]; --j; }
        csr[j + 1] = key;
    }
    for (int p = beg; p < end; ++p) csr[p] = src[csr[p]];
}

// ---------------- aggregation: edge-order sequential f32 adds ----------------
__global__ __launch_bounds__(256) void k_agg(const float* __restrict__ X,
                                             const int* __restrict__ row_start,
                                             const int* __restrict__ csr_src,
                                             float* __restrict__ AGG) {
    int wave = threadIdx.x >> 6;     // 0..3
    int lane = threadIdx.x & 63;
    int n = blockIdx.x * 4 + wave;
    int beg = row_start[n], end = row_start[n + 1];
    float ax = 0.f, ay = 0.f;
    for (int p = beg; p < end; ++p) {
        int nb = csr_src[p];
        const float2 v = *(const float2*)(X + (size_t)nb * DIM + lane * 2);
        ax = __fadd_rn(ax, v.x);
        ay = __fadd_rn(ay, v.y);
    }
    float2 o; o.x = ax; o.y = ay;
    *(float2*)(AGG + (size_t)n * DIM + lane * 2) = o;
}

// ---------------- GEMM1: h1 = relu(bn((1+eps)x + agg) @ W1 + b1)) ----------------
__global__ __launch_bounds__(256) void k_gemm1(const float* __restrict__ X, const float* __restrict__ AGG,
        const float* __restrict__ epss, const float* __restrict__ Ws1, const float* __restrict__ bs1,
        const float* __restrict__ g1s, const float* __restrict__ be1s, const float* __restrict__ rm1s,
        const float* __restrict__ rv1s, int l, float* __restrict__ H1out) {
    __shared__ float As[16][68];
    __shared__ float Bs[16][68];
    const float* W1  = Ws1 + (size_t)l * DIM * H2;
    const float* b1  = bs1 + l * H2;
    const float* g1  = g1s + l * H2;
    const float* be1 = be1s + l * H2;
    const float* rm1 = rm1s + l * H2;
    const float* rv1 = rv1s + l * H2;
    const float ep = __fadd_rn(1.0f, epss[l]);
    const int tid = threadIdx.x;
    const int tx = tid & 15, ty = tid >> 4;
    const int mbase = blockIdx.y * 64;
    const int nbase = blockIdx.x * 64;
    const int lrow = tid >> 2;          // 0..63
    const int lkp  = (tid & 3) * 4;     // 0,4,8,12
    const int bk = tid >> 4;            // 0..15
    const int bc = (tid & 15) * 4;      // 0..60
    float acc[4][4] = {};
    for (int kt = 0; kt < DIM; kt += 16) {
        __syncthreads();
        const float4 xv = *(const float4*)(X   + (size_t)(mbase + lrow) * DIM + kt + lkp);
        const float4 av = *(const float4*)(AGG + (size_t)(mbase + lrow) * DIM + kt + lkp);
        As[lkp + 0][lrow] = __fadd_rn(__fmul_rn(ep, xv.x), av.x);
        As[lkp + 1][lrow] = __fadd_rn(__fmul_rn(ep, xv.y), av.y);
        As[lkp + 2][lrow] = __fadd_rn(__fmul_rn(ep, xv.z), av.z);
        As[lkp + 3][lrow] = __fadd_rn(__fmul_rn(ep, xv.w), av.w);
        *(float4*)&Bs[bk][bc] = *(const float4*)(W1 + (size_t)(kt + bk) * H2 + nbase + bc);
        __syncthreads();
        #pragma unroll
        for (int kk = 0; kk < 16; ++kk) {
            const float4 a = *(const float4*)&As[kk][ty * 4];
            const float4 b = *(const float4*)&Bs[kk][tx * 4];
            const float av4[4] = {a.x, a.y, a.z, a.w};
            const float bv4[4] = {b.x, b.y, b.z, b.w};
            #pragma unroll
            for (int i = 0; i < 4; ++i)
                #pragma unroll
                for (int j = 0; j < 4; ++j)
                    acc[i][j] = __fmaf_rn(av4[i], bv4[j], acc[i][j]);
        }
    }
    const int gr = mbase + ty * 4;
    const int gc = nbase + tx * 4;
    float bb[4], iv[4], gg[4], rr[4], ee[4];
    #pragma unroll
    for (int j = 0; j < 4; ++j) {
        int c = gc + j;
        bb[j] = b1[c];
        iv[j] = __fdiv_rn(1.0f, __fsqrt_rn(__fadd_rn(rv1[c], 1e-5f)));
        gg[j] = g1[c];
        rr[j] = rm1[c];
        ee[j] = be1[c];
    }
    #pragma unroll
    for (int i = 0; i < 4; ++i) {
        float4 o;
        float t;
        t = __fadd_rn(acc[i][0], bb[0]); t = __fsub_rn(t, rr[0]); t = __fmul_rn(t, iv[0]); t = __fmul_rn(t, gg[0]); t = __fadd_rn(t, ee[0]); o.x = fmaxf(t, 0.f);
        t = __fadd_rn(acc[i][1], bb[1]); t = __fsub_rn(t, rr[1]); t = __fmul_rn(t, iv[1]); t = __fmul_rn(t, gg[1]); t = __fadd_rn(t, ee[1]); o.y = fmaxf(t, 0.f);
        t = __fadd_rn(acc[i][2], bb[2]); t = __fsub_rn(t, rr[2]); t = __fmul_rn(t, iv[2]); t = __fmul_rn(t, gg[2]); t = __fadd_rn(t, ee[2]); o.z = fmaxf(t, 0.f);
        t = __fadd_rn(acc[i][3], bb[3]); t = __fsub_rn(t, rr[3]); t = __fmul_rn(t, iv[3]); t = __fmul_rn(t, gg[3]); t = __fadd_rn(t, ee[3]); o.w = fmaxf(t, 0.f);
        *(float4*)(H1out + (size_t)(gr + i) * H2 + gc) = o;
    }
}

// ---------------- GEMM2: x = relu(bn(h1 @ W2 + b2)) ----------------
__global__ __launch_bounds__(256) void k_gemm2(const float* __restrict__ H1, const float* __restrict__ Ws2,
        const float* __restrict__ bs2, const float* __restrict__ gbn, const float* __restrict__ bbn,
        const float* __restrict__ rmbn, const float* __restrict__ rvbn, int l, float* __restrict__ Xout) {
    __shared__ float As[16][68];
    __shared__ float Bs[16][68];
    const float* W2 = Ws2 + (size_t)l * H2 * HID;
    const float* b2 = bs2 + l * HID;
    const float* g  = gbn + l * HID;
    const float* be = bbn + l * HID;
    const float* rm = rmbn + l * HID;
    const float* rv = rvbn + l * HID;
    const int tid = threadIdx.x;
    const int tx = tid & 15, ty = tid >> 4;
    const int mbase = blockIdx.y * 64;
    const int nbase = blockIdx.x * 64;
    const int lrow = tid >> 2;
    const int lkp  = (tid & 3) * 4;
    const int bk = tid >> 4;
    const int bc = (tid & 15) * 4;
    float acc[4][4] = {};
    for (int kt = 0; kt < H2; kt += 16) {
        __syncthreads();
        const float4 hv = *(const float4*)(H1 + (size_t)(mbase + lrow) * H2 + kt + lkp);
        As[lkp + 0][lrow] = hv.x;
        As[lkp + 1][lrow] = hv.y;
        As[lkp + 2][lrow] = hv.z;
        As[lkp + 3][lrow] = hv.w;
        *(float4*)&Bs[bk][bc] = *(const float4*)(W2 + (size_t)(kt + bk) * HID + nbase + bc);
        __syncthreads();
        #pragma unroll
        for (int kk = 0; kk < 16; ++kk) {
            const float4 a = *(const float4*)&As[kk][ty * 4];
            const float4 b = *(const float4*)&Bs[kk][tx * 4];
            const float av4[4] = {a.x, a.y, a.z, a.w};
            const float bv4[4] = {b.x, b.y, b.z, b.w};
            #pragma unroll
            for (int i = 0; i < 4; ++i)
                #pragma unroll
                for (int j = 0; j < 4; ++j)
                    acc[i][j] = __fmaf_rn(av4[i], bv4[j], acc[i][j]);
        }
    }
    const int gr = mbase + ty * 4;
    const int gc = nbase + tx * 4;
    float bb[4], iv[4], gg[4], rr[4], ee[4];
    #pragma unroll
    for (int j = 0; j < 4; ++j) {
        int c = gc + j;
        bb[j] = b2[c];
        iv[j] = __fdiv_rn(1.0f, __fsqrt_rn(__fadd_rn(rv[c], 1e-5f)));
        gg[j] = g[c];
        rr[j] = rm[c];
        ee[j] = be[c];
    }
    #pragma unroll
    for (int i = 0; i < 4; ++i) {
        float4 o;
        float t;
        t = __fadd_rn(acc[i][0], bb[0]); t = __fsub_rn(t, rr[0]); t = __fmul_rn(t, iv[0]); t = __fmul_rn(t, gg[0]); t = __fadd_rn(t, ee[0]); o.x = fmaxf(t, 0.f);
        t = __fadd_rn(acc[i][1], bb[1]); t = __fsub_rn(t, rr[1]); t = __fmul_rn(t, iv[1]); t = __fmul_rn(t, gg[1]); t = __fadd_rn(t, ee[1]); o.y = fmaxf(t, 0.f);
        t = __fadd_rn(acc[i][2], bb[2]); t = __fsub_rn(t, rr[2]); t = __fmul_rn(t, iv[2]); t = __fmul_rn(t, gg[2]); t = __fadd_rn(t, ee[2]); o.z = fmaxf(t, 0.f);
        t = __fadd_rn(acc[i][3], bb[3]); t = __fsub_rn(t, rr[3]); t = __fmul_rn(t, iv[3]); t = __fmul_rn(t, gg[3]); t = __fadd_rn(t, ee[3]); o.w = fmaxf(t, 0.f);
        *(float4*)(Xout + (size_t)(gr + i) * HID + gc) = o;
    }
}

// ---------------- score: XLA fast-tanh plateau at |p| >= 7.90531110763549805 ----------------
__global__ __launch_bounds__(256) void k_score(const float* __restrict__ X, const float* __restrict__ AGG,
        const float* __restrict__ Wrel, const float* __restrict__ brel, const float* __restrict__ Wroot,
        float* __restrict__ S) {
    __shared__ float wr[128], wo[128];
    int t = threadIdx.x;
    if (t < 128) { wr[t] = Wrel[t]; wo[t] = Wroot[t]; }
    __syncthreads();
    int n = blockIdx.x * 256 + t;
    const float* a = AGG + (size_t)n * HID;
    const float* x = X + (size_t)n * HID;
    float p1 = 0.f, p2 = 0.f;
    #pragma unroll 8
    for (int k = 0; k < HID; ++k) p1 = __fmaf_rn(a[k], wr[k], p1);
    #pragma unroll 8
    for (int k = 0; k < HID; ++k) p2 = __fmaf_rn(x[k], wo[k], p2);
    float pp = __fadd_rn(__fadd_rn(p1, brel[0]), p2);
    // XLA/Eigen fast-tanh clamps input to +-7.90531110763549805 -> flat plateau (tie class)
    const float PC = 7.90531110763549805f;
    float s;
    if (pp >= PC)       s = 1.0f;
    else if (pp <= -PC) s = -1.0f;
    else                s = (float)tanh((double)pp);
    S[n] = s;
}

// ---------------- SAGPool top-K on f32 score (value desc, index asc) + pool ----------------
__global__ __launch_bounds__(512) void k_pool(const float* __restrict__ X, const float* __restrict__ S,
                                              float* __restrict__ EMB, double* __restrict__ EMB64) {
    __shared__ unsigned key[512];
    __shared__ double w[512];
    __shared__ double red[4][128];
    const int b = blockIdx.x, tid = threadIdx.x;
    float v = S[b * NNODE + tid];
    unsigned u = __float_as_uint(v);
    unsigned o = (u & 0x80000000u) ? ~u : (u | 0x80000000u);  // order-preserving map
    key[tid] = o;
    __syncthreads();
    int rank = 0;
    for (int j = 0; j < NNODE; ++j) {
        unsigned kj = key[j];
        rank += (int)((kj > o) || (kj == o && j < tid));
    }
    w[tid] = (rank < KSEL) ? (double)v : 0.0;
    __syncthreads();
    const int jgrp = tid >> 7;      // 0..3
    const int col = tid & 127;
    double acc = 0.0;
    for (int i = jgrp; i < NNODE; i += 4) {
        acc += (double)X[((size_t)b * NNODE + i) * HID + col] * w[i];
    }
    red[jgrp][col] = acc;
    __syncthreads();
    if (jgrp == 0) {
        double e = red[0][col] + red[1][col] + red[2][col] + red[3][col];
        EMB[b * HID + col] = (float)e;
        EMB64[b * HID + col] = e;
    }
}

// ---------------- head (f64) ----------------
__global__ __launch_bounds__(128) void k_head(const double* __restrict__ EMB64,
        const float* __restrict__ W1, const float* __restrict__ b1,
        const float* __restrict__ g, const float* __restrict__ be,
        const float* __restrict__ rm, const float* __restrict__ rv,
        const float* __restrict__ W2, const float* __restrict__ b2,
        float* __restrict__ LOGITS) {
    __shared__ double e[128];
    __shared__ double h[128];
    const int b = blockIdx.x, t = threadIdx.x;
    e[t] = EMB64[b * HID + t];
    __syncthreads();
    double acc = 0.0;
    for (int k = 0; k < HID; ++k) acc += e[k] * (double)W1[k * HID + t];
    acc += (double)b1[t];
    double inv = 1.0 / sqrt((double)rv[t] + 1e-5);
    acc = (acc - (double)rm[t]) * inv * (double)g[t] + (double)be[t];
    h[t] = fmax(acc, 0.0);
    __syncthreads();
    if (t < OUTC) {
        double a2 = (double)b2[t];
        for (int k = 0; k < HID; ++k) a2 += h[k] * (double)W2[k * OUTC + t];
        LOGITS[b * OUTC + t] = (float)a2;
    }
}

extern "C" void kernel_launch(void* const* d_in, const int* in_sizes, int n_in,
                              void* d_out, int out_size, void* d_ws, size_t ws_size,
                              hipStream_t stream) {
    const float* x     = (const float*)d_in[0];
    const int*   edge  = (const int*)d_in[1];
    const int*   src   = edge;
    const int*   dst   = edge + EDGES;
    const float* epss  = (const float*)d_in[3];
    const float* Ws1   = (const float*)d_in[4];
    const float* bs1   = (const float*)d_in[5];
    const float* g1s   = (const float*)d_in[6];
    const float* be1s  = (const float*)d_in[7];
    const float* rm1s  = (const float*)d_in[8];
    const float* rv1s  = (const float*)d_in[9];
    const float* Ws2   = (const float*)d_in[10];
    const float* bs2   = (const float*)d_in[11];
    const float* gbn   = (const float*)d_in[12];
    const float* bbn   = (const float*)d_in[13];
    const float* rmbn  = (const float*)d_in[14];
    const float* rvbn  = (const float*)d_in[15];
    const float* Wrel  = (const float*)d_in[16];
    const float* brel  = (const float*)d_in[17];
    const float* Wroot = (const float*)d_in[18];
    const float* W_lin1= (const float*)d_in[19];
    const float* b_lin1= (const float*)d_in[20];
    const float* g_h   = (const float*)d_in[21];
    const float* be_h  = (const float*)d_in[22];
    const float* rm_h  = (const float*)d_in[23];
    const float* rv_h  = (const float*)d_in[24];
    const float* W_lin2= (const float*)d_in[25];
    const float* b_lin2= (const float*)d_in[26];

    char* ws = (char*)d_ws;
    float*  x_cur    = (float*) (ws);                    // 32 MB
    float*  agg      = (float*) (ws + 33554432);         // 32 MB
    float*  h1       = (float*) (ws + 67108864);         // 64 MB
    float*  s32      = (float*) (ws + 134217728);        // 256 KB
    double* emb64    = (double*)(ws + 134479872);        // 128 KB
    int*    row_start= (int*)   (ws + 134610944);        // 256 KB + 4
    int*    cursor   = (int*)   (ws + 134877184);        // 256 KB
    int*    counts   = (int*)   (ws + 135139328);        // 256 KB
    int*    csr     = (int*)    (ws + 135401472);        // 4 MB

    float* emb    = (float*)d_out;
    float* logits = (float*)d_out + BGRAPH * HID;

    // ---- CSR (by dst) build: counts -> scan -> fill(eids) -> sort rows (edge order) ----
    hipMemsetAsync(counts, 0, NT_ * sizeof(int), stream);
    k_count<<<EDGES / 256, 256, 0, stream>>>(dst, counts);
    k_scan<<<1, 1024, 0, stream>>>(counts, row_start, cursor);
    k_fill<<<EDGES / 256, 256, 0, stream>>>(dst, cursor, csr);
    k_sortrows<<<NT_ / 256, 256, 0, stream>>>(src, row_start, csr);

    // ---- layer 0 ----
    k_agg<<<NT_ / 4, 256, 0, stream>>>(x, row_start, csr, agg);
    k_gemm1<<<dim3(4, NT_ / 64), 256, 0, stream>>>(x, agg, epss, Ws1, bs1, g1s, be1s, rm1s, rv1s, 0, h1);
    k_gemm2<<<dim3(2, NT_ / 64), 256, 0, stream>>>(h1, Ws2, bs2, gbn, bbn, rmbn, rvbn, 0, x_cur);
    // ---- layer 1 ----
    k_agg<<<NT_ / 4, 256, 0, stream>>>(x_cur, row_start, csr, agg);
    k_gemm1<<<dim3(4, NT_ / 64), 256, 0, stream>>>(x_cur, agg, epss, Ws1, bs1, g1s, be1s, rm1s, rv1s, 1, h1);
    k_gemm2<<<dim3(2, NT_ / 64), 256, 0, stream>>>(h1, Ws2, bs2, gbn, bbn, rmbn, rvbn, 1, x_cur);
    // ---- scoring + pool + head ----
    k_agg<<<NT_ / 4, 256, 0, stream>>>(x_cur, row_start, csr, agg);
    k_score<<<NT_ / 256, 256, 0, stream>>>(x_cur, agg, Wrel, brel, Wroot, s32);
    k_pool<<<BGRAPH, 512, 0, stream>>>(x_cur, s32, emb, emb64);
    k_head<<<BGRAPH, 128, 0, stream>>>(emb64, W_lin1, b_lin1, g_h, be_h, rm_h, rv_h, W_lin2, b_lin2, logits);
}

// Round 7
// 606.570 us; speedup vs baseline: 1.3295x; 1.3295x over previous
//
#include <hip/hip_runtime.h>
#include <hip/hip_bf16.h>
#include <stdint.h>
#include <math.h>

#define NT_ 65536
#define BGRAPH 128
#define NNODE 512
#define DIM 128
#define HID 128
#define H2 256
#define EDGES 1048576
#define KSEL 256
#define OUTC 10
#define SCAP 48

typedef float v2f __attribute__((ext_vector_type(2)));

// ---------------- CSR build ----------------
__global__ void k_count(const int* __restrict__ dst, int* __restrict__ counts) {
    int e = blockIdx.x * blockDim.x + threadIdx.x;
    if (e < EDGES) atomicAdd(&counts[dst[e]], 1);
}

__global__ __launch_bounds__(1024) void k_scan(const int* __restrict__ counts,
                                               int* __restrict__ row_start,
                                               int* __restrict__ cursor) {
    __shared__ int part[1024];
    int t = threadIdx.x;
    int base = t * 64;
    int s = 0;
    #pragma unroll
    for (int i = 0; i < 64; ++i) s += counts[base + i];
    part[t] = s;
    __syncthreads();
    for (int off = 1; off < 1024; off <<= 1) {
        int v = (t >= off) ? part[t - off] : 0;
        __syncthreads();
        part[t] += v;
        __syncthreads();
    }
    int run = part[t] - s;
    for (int i = 0; i < 64; ++i) {
        row_start[base + i] = run;
        cursor[base + i] = run;
        run += counts[base + i];
    }
    if (t == 1023) row_start[NT_] = part[1023];
}

__global__ void k_fill(const int* __restrict__ dst,
                       int* __restrict__ cursor, int* __restrict__ csr) {
    int e = blockIdx.x * blockDim.x + threadIdx.x;
    if (e < EDGES) {
        int d = dst[e];
        int pos = atomicAdd(&cursor[d], 1);
        csr[pos] = e;
    }
}

// sort each row's edge-ids ascending in LDS (restore edge order), then map eid->src
__global__ __launch_bounds__(256) void k_sortrows(const int* __restrict__ src,
                                                  const int* __restrict__ row_start,
                                                  int* __restrict__ csr) {
    __shared__ int buf[256 * SCAP];   // 48 KB
    int t = threadIdx.x;
    int n = blockIdx.x * 256 + t;
    int beg = row_start[n], end = row_start[n + 1];
    int d = end - beg;
    int* my = &buf[t * SCAP];
    if (d <= SCAP) {
        for (int i = 0; i < d; ++i) my[i] = csr[beg + i];
        for (int i = 1; i < d; ++i) {
            int key = my[i];
            int j = i - 1;
            while (j >= 0 && my[j] > key) { my[j + 1] = my[j]; --j; }
            my[j + 1] = key;
        }
        for (int i = 0; i < d; ++i) csr[beg + i] = src[my[i]];
    } else {
        for (int i = beg + 1; i < end; ++i) {
            int key = csr[i];
            int j = i - 1;
            while (j >= beg && csr[j] > key) { csr[j + 1] = csr[j]; --j; }
            csr[j + 1] = key;
        }
        for (int p = beg; p < end; ++p) csr[p] = src[csr[p]];
    }
}

// ---------------- aggregation: edge-order sequential f32 adds, 8-wide pipelined ----------------
__global__ __launch_bounds__(256) void k_agg(const float* __restrict__ X,
                                             const int* __restrict__ row_start,
                                             const int* __restrict__ csr_src,
                                             float* __restrict__ AGG) {
    // XCD swizzle: gridDim.x = 16384 (multiple of 8) -> contiguous chunk per XCD
    int bid = blockIdx.x;
    int wg = (bid & 7) * (16384 >> 3) + (bid >> 3);
    int wave = threadIdx.x >> 6;
    int lane = threadIdx.x & 63;
    int n = wg * 4 + wave;
    int beg = row_start[n], end = row_start[n + 1];
    const size_t co = (size_t)(lane * 2);
    float ax = 0.f, ay = 0.f;
    int p = beg;
    for (; p + 8 <= end; p += 8) {
        int n0 = csr_src[p+0], n1 = csr_src[p+1], n2 = csr_src[p+2], n3 = csr_src[p+3];
        int n4 = csr_src[p+4], n5 = csr_src[p+5], n6 = csr_src[p+6], n7 = csr_src[p+7];
        float2 v0 = *(const float2*)(X + (size_t)n0 * DIM + co);
        float2 v1 = *(const float2*)(X + (size_t)n1 * DIM + co);
        float2 v2 = *(const float2*)(X + (size_t)n2 * DIM + co);
        float2 v3 = *(const float2*)(X + (size_t)n3 * DIM + co);
        float2 v4 = *(const float2*)(X + (size_t)n4 * DIM + co);
        float2 v5 = *(const float2*)(X + (size_t)n5 * DIM + co);
        float2 v6 = *(const float2*)(X + (size_t)n6 * DIM + co);
        float2 v7 = *(const float2*)(X + (size_t)n7 * DIM + co);
        ax = __fadd_rn(ax, v0.x); ay = __fadd_rn(ay, v0.y);
        ax = __fadd_rn(ax, v1.x); ay = __fadd_rn(ay, v1.y);
        ax = __fadd_rn(ax, v2.x); ay = __fadd_rn(ay, v2.y);
        ax = __fadd_rn(ax, v3.x); ay = __fadd_rn(ay, v3.y);
        ax = __fadd_rn(ax, v4.x); ay = __fadd_rn(ay, v4.y);
        ax = __fadd_rn(ax, v5.x); ay = __fadd_rn(ay, v5.y);
        ax = __fadd_rn(ax, v6.x); ay = __fadd_rn(ay, v6.y);
        ax = __fadd_rn(ax, v7.x); ay = __fadd_rn(ay, v7.y);
    }
    for (; p + 4 <= end; p += 4) {
        int n0 = csr_src[p+0], n1 = csr_src[p+1], n2 = csr_src[p+2], n3 = csr_src[p+3];
        float2 v0 = *(const float2*)(X + (size_t)n0 * DIM + co);
        float2 v1 = *(const float2*)(X + (size_t)n1 * DIM + co);
        float2 v2 = *(const float2*)(X + (size_t)n2 * DIM + co);
        float2 v3 = *(const float2*)(X + (size_t)n3 * DIM + co);
        ax = __fadd_rn(ax, v0.x); ay = __fadd_rn(ay, v0.y);
        ax = __fadd_rn(ax, v1.x); ay = __fadd_rn(ay, v1.y);
        ax = __fadd_rn(ax, v2.x); ay = __fadd_rn(ay, v2.y);
        ax = __fadd_rn(ax, v3.x); ay = __fadd_rn(ay, v3.y);
    }
    for (; p < end; ++p) {
        int nb = csr_src[p];
        float2 v = *(const float2*)(X + (size_t)nb * DIM + co);
        ax = __fadd_rn(ax, v.x); ay = __fadd_rn(ay, v.y);
    }
    float2 o; o.x = ax; o.y = ay;
    *(float2*)(AGG + (size_t)n * DIM + co) = o;
}

// ---------------- GEMM1: h1 = relu(bn((1+eps)x + agg) @ W1 + b1)), 128x64 tile ----------------
__global__ __launch_bounds__(256) void k_gemm1(const float* __restrict__ X, const float* __restrict__ AGG,
        const float* __restrict__ epss, const float* __restrict__ Ws1, const float* __restrict__ bs1,
        const float* __restrict__ g1s, const float* __restrict__ be1s, const float* __restrict__ rm1s,
        const float* __restrict__ rv1s, int l, float* __restrict__ H1out) {
    __shared__ float As[16][132];
    __shared__ float Bs[16][68];
    const float* W1  = Ws1 + (size_t)l * DIM * H2;
    const float* b1  = bs1 + l * H2;
    const float* g1  = g1s + l * H2;
    const float* be1 = be1s + l * H2;
    const float* rm1 = rm1s + l * H2;
    const float* rv1 = rv1s + l * H2;
    const float ep = __fadd_rn(1.0f, epss[l]);
    // grid: 2048 blocks (512 M-tiles x 4 N-tiles), XCD swizzle
    int bid = blockIdx.x;
    int wg = (bid & 7) * (2048 >> 3) + (bid >> 3);
    const int mbase = (wg >> 2) * 128;
    const int nbase = (wg & 3) * 64;
    const int tid = threadIdx.x;
    const int srow = tid >> 1;          // 0..127
    const int sk   = (tid & 1) * 8;     // 0 or 8
    const int bk = tid >> 4;            // 0..15
    const int bc = (tid & 15) * 4;      // 0..60
    const int ty = tid >> 4;            // 0..15 -> rows ty*8..+7
    const int tx = tid & 15;            // cols tx*4..+3
    v2f acc[8][2] = {};
    for (int kt = 0; kt < DIM; kt += 16) {
        __syncthreads();
        const float* xr = X   + (size_t)(mbase + srow) * DIM + kt + sk;
        const float* ar = AGG + (size_t)(mbase + srow) * DIM + kt + sk;
        const float4 x0 = *(const float4*)(xr);
        const float4 x1 = *(const float4*)(xr + 4);
        const float4 a0 = *(const float4*)(ar);
        const float4 a1 = *(const float4*)(ar + 4);
        As[sk + 0][srow] = __fadd_rn(__fmul_rn(ep, x0.x), a0.x);
        As[sk + 1][srow] = __fadd_rn(__fmul_rn(ep, x0.y), a0.y);
        As[sk + 2][srow] = __fadd_rn(__fmul_rn(ep, x0.z), a0.z);
        As[sk + 3][srow] = __fadd_rn(__fmul_rn(ep, x0.w), a0.w);
        As[sk + 4][srow] = __fadd_rn(__fmul_rn(ep, x1.x), a1.x);
        As[sk + 5][srow] = __fadd_rn(__fmul_rn(ep, x1.y), a1.y);
        As[sk + 6][srow] = __fadd_rn(__fmul_rn(ep, x1.z), a1.z);
        As[sk + 7][srow] = __fadd_rn(__fmul_rn(ep, x1.w), a1.w);
        *(float4*)&Bs[bk][bc] = *(const float4*)(W1 + (size_t)(kt + bk) * H2 + nbase + bc);
        __syncthreads();
        #pragma unroll
        for (int kk = 0; kk < 16; ++kk) {
            const float4 aA = *(const float4*)&As[kk][ty * 8];
            const float4 aB = *(const float4*)&As[kk][ty * 8 + 4];
            const float4 b  = *(const float4*)&Bs[kk][tx * 4];
            v2f b01; b01[0] = b.x; b01[1] = b.y;
            v2f b23; b23[0] = b.z; b23[1] = b.w;
            const float arr[8] = {aA.x, aA.y, aA.z, aA.w, aB.x, aB.y, aB.z, aB.w};
            #pragma unroll
            for (int i = 0; i < 8; ++i) {
                v2f ai; ai[0] = arr[i]; ai[1] = arr[i];
                acc[i][0] = __builtin_elementwise_fma(ai, b01, acc[i][0]);
                acc[i][1] = __builtin_elementwise_fma(ai, b23, acc[i][1]);
            }
        }
    }
    const int gc = nbase + tx * 4;
    float bb[4], iv[4], gg[4], rr[4], ee[4];
    #pragma unroll
    for (int j = 0; j < 4; ++j) {
        int c = gc + j;
        bb[j] = b1[c];
        iv[j] = __fdiv_rn(1.0f, __fsqrt_rn(__fadd_rn(rv1[c], 1e-5f)));
        gg[j] = g1[c];
        rr[j] = rm1[c];
        ee[j] = be1[c];
    }
    #pragma unroll
    for (int i = 0; i < 8; ++i) {
        const int gr = mbase + ty * 8 + i;
        float c0 = acc[i][0][0], c1 = acc[i][0][1], c2 = acc[i][1][0], c3 = acc[i][1][1];
        float4 o; float t;
        t = __fadd_rn(c0, bb[0]); t = __fsub_rn(t, rr[0]); t = __fmul_rn(t, iv[0]); t = __fmul_rn(t, gg[0]); t = __fadd_rn(t, ee[0]); o.x = fmaxf(t, 0.f);
        t = __fadd_rn(c1, bb[1]); t = __fsub_rn(t, rr[1]); t = __fmul_rn(t, iv[1]); t = __fmul_rn(t, gg[1]); t = __fadd_rn(t, ee[1]); o.y = fmaxf(t, 0.f);
        t = __fadd_rn(c2, bb[2]); t = __fsub_rn(t, rr[2]); t = __fmul_rn(t, iv[2]); t = __fmul_rn(t, gg[2]); t = __fadd_rn(t, ee[2]); o.z = fmaxf(t, 0.f);
        t = __fadd_rn(c3, bb[3]); t = __fsub_rn(t, rr[3]); t = __fmul_rn(t, iv[3]); t = __fmul_rn(t, gg[3]); t = __fadd_rn(t, ee[3]); o.w = fmaxf(t, 0.f);
        *(float4*)(H1out + (size_t)gr * H2 + gc) = o;
    }
}

// ---------------- GEMM2: x = relu(bn(h1 @ W2 + b2)), 128x64 tile ----------------
__global__ __launch_bounds__(256) void k_gemm2(const float* __restrict__ H1, const float* __restrict__ Ws2,
        const float* __restrict__ bs2, const float* __restrict__ gbn, const float* __restrict__ bbn,
        const float* __restrict__ rmbn, const float* __restrict__ rvbn, int l, float* __restrict__ Xout) {
    __shared__ float As[16][132];
    __shared__ float Bs[16][68];
    const float* W2 = Ws2 + (size_t)l * H2 * HID;
    const float* b2 = bs2 + l * HID;
    const float* g  = gbn + l * HID;
    const float* be = bbn + l * HID;
    const float* rm = rmbn + l * HID;
    const float* rv = rvbn + l * HID;
    // grid: 1024 blocks (512 M-tiles x 2 N-tiles), XCD swizzle
    int bid = blockIdx.x;
    int wg = (bid & 7) * (1024 >> 3) + (bid >> 3);
    const int mbase = (wg >> 1) * 128;
    const int nbase = (wg & 1) * 64;
    const int tid = threadIdx.x;
    const int srow = tid >> 1;
    const int sk   = (tid & 1) * 8;
    const int bk = tid >> 4;
    const int bc = (tid & 15) * 4;
    const int ty = tid >> 4;
    const int tx = tid & 15;
    v2f acc[8][2] = {};
    for (int kt = 0; kt < H2; kt += 16) {
        __syncthreads();
        const float* hr = H1 + (size_t)(mbase + srow) * H2 + kt + sk;
        const float4 h0 = *(const float4*)(hr);
        const float4 h1v = *(const float4*)(hr + 4);
        As[sk + 0][srow] = h0.x;
        As[sk + 1][srow] = h0.y;
        As[sk + 2][srow] = h0.z;
        As[sk + 3][srow] = h0.w;
        As[sk + 4][srow] = h1v.x;
        As[sk + 5][srow] = h1v.y;
        As[sk + 6][srow] = h1v.z;
        As[sk + 7][srow] = h1v.w;
        *(float4*)&Bs[bk][bc] = *(const float4*)(W2 + (size_t)(kt + bk) * HID + nbase + bc);
        __syncthreads();
        #pragma unroll
        for (int kk = 0; kk < 16; ++kk) {
            const float4 aA = *(const float4*)&As[kk][ty * 8];
            const float4 aB = *(const float4*)&As[kk][ty * 8 + 4];
            const float4 b  = *(const float4*)&Bs[kk][tx * 4];
            v2f b01; b01[0] = b.x; b01[1] = b.y;
            v2f b23; b23[0] = b.z; b23[1] = b.w;
            const float arr[8] = {aA.x, aA.y, aA.z, aA.w, aB.x, aB.y, aB.z, aB.w};
            #pragma unroll
            for (int i = 0; i < 8; ++i) {
                v2f ai; ai[0] = arr[i]; ai[1] = arr[i];
                acc[i][0] = __builtin_elementwise_fma(ai, b01, acc[i][0]);
                acc[i][1] = __builtin_elementwise_fma(ai, b23, acc[i][1]);
            }
        }
    }
    const int gc = nbase + tx * 4;
    float bb[4], iv[4], gg[4], rr[4], ee[4];
    #pragma unroll
    for (int j = 0; j < 4; ++j) {
        int c = gc + j;
        bb[j] = b2[c];
        iv[j] = __fdiv_rn(1.0f, __fsqrt_rn(__fadd_rn(rv[c], 1e-5f)));
        gg[j] = g[c];
        rr[j] = rm[c];
        ee[j] = be[c];
    }
    #pragma unroll
    for (int i = 0; i < 8; ++i) {
        const int gr = mbase + ty * 8 + i;
        float c0 = acc[i][0][0], c1 = acc[i][0][1], c2 = acc[i][1][0], c3 = acc[i][1][1];
        float4 o; float t;
        t = __fadd_rn(c0, bb[0]); t = __fsub_rn(t, rr[0]); t = __fmul_rn(t, iv[0]); t = __fmul_rn(t, gg[0]); t = __fadd_rn(t, ee[0]); o.x = fmaxf(t, 0.f);
        t = __fadd_rn(c1, bb[1]); t = __fsub_rn(t, rr[1]); t = __fmul_rn(t, iv[1]); t = __fmul_rn(t, gg[1]); t = __fadd_rn(t, ee[1]); o.y = fmaxf(t, 0.f);
        t = __fadd_rn(c2, bb[2]); t = __fsub_rn(t, rr[2]); t = __fmul_rn(t, iv[2]); t = __fmul_rn(t, gg[2]); t = __fadd_rn(t, ee[2]); o.z = fmaxf(t, 0.f);
        t = __fadd_rn(c3, bb[3]); t = __fsub_rn(t, rr[3]); t = __fmul_rn(t, iv[3]); t = __fmul_rn(t, gg[3]); t = __fadd_rn(t, ee[3]); o.w = fmaxf(t, 0.f);
        *(float4*)(Xout + (size_t)gr * HID + gc) = o;
    }
}

// ---------------- score: XLA fast-tanh plateau at |p| >= 7.90531110763549805 ----------------
__global__ __launch_bounds__(256) void k_score(const float* __restrict__ X, const float* __restrict__ AGG,
        const float* __restrict__ Wrel, const float* __restrict__ brel, const float* __restrict__ Wroot,
        float* __restrict__ S) {
    __shared__ float wr[128], wo[128];
    int t = threadIdx.x;
    if (t < 128) { wr[t] = Wrel[t]; wo[t] = Wroot[t]; }
    __syncthreads();
    int n = blockIdx.x * 256 + t;
    const float* a = AGG + (size_t)n * HID;
    const float* x = X + (size_t)n * HID;
    float p1 = 0.f, p2 = 0.f;
    #pragma unroll 8
    for (int k = 0; k < HID; ++k) p1 = __fmaf_rn(a[k], wr[k], p1);
    #pragma unroll 8
    for (int k = 0; k < HID; ++k) p2 = __fmaf_rn(x[k], wo[k], p2);
    float pp = __fadd_rn(__fadd_rn(p1, brel[0]), p2);
    const float PC = 7.90531110763549805f;
    float s;
    if (pp >= PC)       s = 1.0f;
    else if (pp <= -PC) s = -1.0f;
    else                s = (float)tanh((double)pp);
    S[n] = s;
}

// ---------------- SAGPool top-K on f32 score (value desc, index asc) + pool ----------------
__global__ __launch_bounds__(512) void k_pool(const float* __restrict__ X, const float* __restrict__ S,
                                              float* __restrict__ EMB, double* __restrict__ EMB64) {
    __shared__ unsigned key[512];
    __shared__ double w[512];
    __shared__ double red[4][128];
    const int b = blockIdx.x, tid = threadIdx.x;
    float v = S[b * NNODE + tid];
    unsigned u = __float_as_uint(v);
    unsigned o = (u & 0x80000000u) ? ~u : (u | 0x80000000u);
    key[tid] = o;
    __syncthreads();
    int rank = 0;
    for (int j = 0; j < NNODE; ++j) {
        unsigned kj = key[j];
        rank += (int)((kj > o) || (kj == o && j < tid));
    }
    w[tid] = (rank < KSEL) ? (double)v : 0.0;
    __syncthreads();
    const int jgrp = tid >> 7;
    const int col = tid & 127;
    double acc = 0.0;
    for (int i = jgrp; i < NNODE; i += 4) {
        acc += (double)X[((size_t)b * NNODE + i) * HID + col] * w[i];
    }
    red[jgrp][col] = acc;
    __syncthreads();
    if (jgrp == 0) {
        double e = red[0][col] + red[1][col] + red[2][col] + red[3][col];
        EMB[b * HID + col] = (float)e;
        EMB64[b * HID + col] = e;
    }
}

// ---------------- head (f64) ----------------
__global__ __launch_bounds__(128) void k_head(const double* __restrict__ EMB64,
        const float* __restrict__ W1, const float* __restrict__ b1,
        const float* __restrict__ g, const float* __restrict__ be,
        const float* __restrict__ rm, const float* __restrict__ rv,
        const float* __restrict__ W2, const float* __restrict__ b2,
        float* __restrict__ LOGITS) {
    __shared__ double e[128];
    __shared__ double h[128];
    const int b = blockIdx.x, t = threadIdx.x;
    e[t] = EMB64[b * HID + t];
    __syncthreads();
    double acc = 0.0;
    for (int k = 0; k < HID; ++k) acc += e[k] * (double)W1[k * HID + t];
    acc += (double)b1[t];
    double inv = 1.0 / sqrt((double)rv[t] + 1e-5);
    acc = (acc - (double)rm[t]) * inv * (double)g[t] + (double)be[t];
    h[t] = fmax(acc, 0.0);
    __syncthreads();
    if (t < OUTC) {
        double a2 = (double)b2[t];
        for (int k = 0; k < HID; ++k) a2 += h[k] * (double)W2[k * OUTC + t];
        LOGITS[b * OUTC + t] = (float)a2;
    }
}

extern "C" void kernel_launch(void* const* d_in, const int* in_sizes, int n_in,
                              void* d_out, int out_size, void* d_ws, size_t ws_size,
                              hipStream_t stream) {
    const float* x     = (const float*)d_in[0];
    const int*   edge  = (const int*)d_in[1];
    const int*   src   = edge;
    const int*   dst   = edge + EDGES;
    const float* epss  = (const float*)d_in[3];
    const float* Ws1   = (const float*)d_in[4];
    const float* bs1   = (const float*)d_in[5];
    const float* g1s   = (const float*)d_in[6];
    const float* be1s  = (const float*)d_in[7];
    const float* rm1s  = (const float*)d_in[8];
    const float* rv1s  = (const float*)d_in[9];
    const float* Ws2   = (const float*)d_in[10];
    const float* bs2   = (const float*)d_in[11];
    const float* gbn   = (const float*)d_in[12];
    const float* bbn   = (const float*)d_in[13];
    const float* rmbn  = (const float*)d_in[14];
    const float* rvbn  = (const float*)d_in[15];
    const float* Wrel  = (const float*)d_in[16];
    const float* brel  = (const float*)d_in[17];
    const float* Wroot = (const float*)d_in[18];
    const float* W_lin1= (const float*)d_in[19];
    const float* b_lin1= (const float*)d_in[20];
    const float* g_h   = (const float*)d_in[21];
    const float* be_h  = (const float*)d_in[22];
    const float* rm_h  = (const float*)d_in[23];
    const float* rv_h  = (const float*)d_in[24];
    const float* W_lin2= (const float*)d_in[25];
    const float* b_lin2= (const float*)d_in[26];

    char* ws = (char*)d_ws;
    float*  x_cur    = (float*) (ws);                    // 32 MB
    float*  agg      = (float*) (ws + 33554432);         // 32 MB
    float*  h1       = (float*) (ws + 67108864);         // 64 MB
    float*  s32      = (float*) (ws + 134217728);        // 256 KB
    double* emb64    = (double*)(ws + 134479872);        // 128 KB
    int*    row_start= (int*)   (ws + 134610944);        // 256 KB + 4
    int*    cursor   = (int*)   (ws + 134877184);        // 256 KB
    int*    counts   = (int*)   (ws + 135139328);        // 256 KB
    int*    csr     = (int*)    (ws + 135401472);        // 4 MB

    float* emb    = (float*)d_out;
    float* logits = (float*)d_out + BGRAPH * HID;

    // ---- CSR (by dst): counts -> scan -> fill(eids) -> LDS row sort (edge order) ----
    hipMemsetAsync(counts, 0, NT_ * sizeof(int), stream);
    k_count<<<EDGES / 256, 256, 0, stream>>>(dst, counts);
    k_scan<<<1, 1024, 0, stream>>>(counts, row_start, cursor);
    k_fill<<<EDGES / 256, 256, 0, stream>>>(dst, cursor, csr);
    k_sortrows<<<NT_ / 256, 256, 0, stream>>>(src, row_start, csr);

    // ---- layer 0 ----
    k_agg<<<NT_ / 4, 256, 0, stream>>>(x, row_start, csr, agg);
    k_gemm1<<<2048, 256, 0, stream>>>(x, agg, epss, Ws1, bs1, g1s, be1s, rm1s, rv1s, 0, h1);
    k_gemm2<<<1024, 256, 0, stream>>>(h1, Ws2, bs2, gbn, bbn, rmbn, rvbn, 0, x_cur);
    // ---- layer 1 ----
    k_agg<<<NT_ / 4, 256, 0, stream>>>(x_cur, row_start, csr, agg);
    k_gemm1<<<2048, 256, 0, stream>>>(x_cur, agg, epss, Ws1, bs1, g1s, be1s, rm1s, rv1s, 1, h1);
    k_gemm2<<<1024, 256, 0, stream>>>(h1, Ws2, bs2, gbn, bbn, rmbn, rvbn, 1, x_cur);
    // ---- scoring + pool + head ----
    k_agg<<<NT_ / 4, 256, 0, stream>>>(x_cur, row_start, csr, agg);
    k_score<<<NT_ / 256, 256, 0, stream>>>(x_cur, agg, Wrel, brel, Wroot, s32);
    k_pool<<<BGRAPH, 512, 0, stream>>>(x_cur, s32, emb, emb64);
    k_head<<<BGRAPH, 128, 0, stream>>>(emb64, W_lin1, b_lin1, g_h, be_h, rm_h, rv_h, W_lin2, b_lin2, logits);
}

// Round 8
// 546.983 us; speedup vs baseline: 1.4743x; 1.1089x over previous
//
#include <hip/hip_runtime.h>
#include <hip/hip_bf16.h>
#include <stdint.h>
#include <math.h>

#define NT_ 65536
#define BGRAPH 128
#define NNODE 512
#define DIM 128
#define HID 128
#define H2 256
#define EDGES 1048576
#define KSEL 256
#define OUTC 10
#define SCAP 48

typedef float v2f __attribute__((ext_vector_type(2)));

// ---------------- CSR build ----------------
__global__ void k_count(const int* __restrict__ dst, int* __restrict__ counts) {
    int e = blockIdx.x * blockDim.x + threadIdx.x;
    if (e < EDGES) atomicAdd(&counts[dst[e]], 1);
}

__global__ __launch_bounds__(1024) void k_scan(const int* __restrict__ counts,
                                               int* __restrict__ row_start,
                                               int* __restrict__ cursor) {
    __shared__ int part[1024];
    int t = threadIdx.x;
    int base = t * 64;
    int s = 0;
    #pragma unroll
    for (int i = 0; i < 64; ++i) s += counts[base + i];
    part[t] = s;
    __syncthreads();
    for (int off = 1; off < 1024; off <<= 1) {
        int v = (t >= off) ? part[t - off] : 0;
        __syncthreads();
        part[t] += v;
        __syncthreads();
    }
    int run = part[t] - s;
    for (int i = 0; i < 64; ++i) {
        row_start[base + i] = run;
        cursor[base + i] = run;
        run += counts[base + i];
    }
    if (t == 1023) row_start[NT_] = part[1023];
}

__global__ void k_fill(const int* __restrict__ dst,
                       int* __restrict__ cursor, int* __restrict__ csr) {
    int e = blockIdx.x * blockDim.x + threadIdx.x;
    if (e < EDGES) {
        int d = dst[e];
        int pos = atomicAdd(&cursor[d], 1);
        csr[pos] = e;
    }
}

// sort each row's edge-ids ascending in LDS (restore edge order), then map eid->src
__global__ __launch_bounds__(256) void k_sortrows(const int* __restrict__ src,
                                                  const int* __restrict__ row_start,
                                                  int* __restrict__ csr) {
    __shared__ int buf[256 * SCAP];   // 48 KB
    int t = threadIdx.x;
    int n = blockIdx.x * 256 + t;
    int beg = row_start[n], end = row_start[n + 1];
    int d = end - beg;
    int* my = &buf[t * SCAP];
    if (d <= SCAP) {
        for (int i = 0; i < d; ++i) my[i] = csr[beg + i];
        for (int i = 1; i < d; ++i) {
            int key = my[i];
            int j = i - 1;
            while (j >= 0 && my[j] > key) { my[j + 1] = my[j]; --j; }
            my[j + 1] = key;
        }
        for (int i = 0; i < d; ++i) csr[beg + i] = src[my[i]];
    } else {
        for (int i = beg + 1; i < end; ++i) {
            int key = csr[i];
            int j = i - 1;
            while (j >= beg && csr[j] > key) { csr[j + 1] = csr[j]; --j; }
            csr[j + 1] = key;
        }
        for (int p = beg; p < end; ++p) csr[p] = src[csr[p]];
    }
}

// ---------------- aggregation: 2 nodes/wave, float4 lanes, edge-order f32 chain ----------------
__global__ __launch_bounds__(256) void k_agg(const float* __restrict__ X,
                                             const int* __restrict__ row_start,
                                             const int* __restrict__ csr_src,
                                             float* __restrict__ AGG) {
    // grid 8192 (mult of 8), XCD swizzle: contiguous chunk per XCD
    int bid = blockIdx.x;
    int wg = (bid & 7) * 1024 + (bid >> 3);
    int wave = threadIdx.x >> 6;
    int lane = threadIdx.x & 63;
    int half = lane >> 5;
    int l32 = lane & 31;
    int n = wg * 8 + wave * 2 + half;
    int beg = row_start[n], end = row_start[n + 1];
    const size_t co = (size_t)(l32 * 4);
    float a0 = 0.f, a1 = 0.f, a2 = 0.f, a3 = 0.f;
    int p = beg;
    for (; p + 8 <= end; p += 8) {
        int n0 = csr_src[p+0], n1 = csr_src[p+1], n2 = csr_src[p+2], n3 = csr_src[p+3];
        int n4 = csr_src[p+4], n5 = csr_src[p+5], n6 = csr_src[p+6], n7 = csr_src[p+7];
        float4 v0 = *(const float4*)(X + (size_t)n0 * DIM + co);
        float4 v1 = *(const float4*)(X + (size_t)n1 * DIM + co);
        float4 v2 = *(const float4*)(X + (size_t)n2 * DIM + co);
        float4 v3 = *(const float4*)(X + (size_t)n3 * DIM + co);
        float4 v4 = *(const float4*)(X + (size_t)n4 * DIM + co);
        float4 v5 = *(const float4*)(X + (size_t)n5 * DIM + co);
        float4 v6 = *(const float4*)(X + (size_t)n6 * DIM + co);
        float4 v7 = *(const float4*)(X + (size_t)n7 * DIM + co);
        a0 = __fadd_rn(a0, v0.x); a1 = __fadd_rn(a1, v0.y); a2 = __fadd_rn(a2, v0.z); a3 = __fadd_rn(a3, v0.w);
        a0 = __fadd_rn(a0, v1.x); a1 = __fadd_rn(a1, v1.y); a2 = __fadd_rn(a2, v1.z); a3 = __fadd_rn(a3, v1.w);
        a0 = __fadd_rn(a0, v2.x); a1 = __fadd_rn(a1, v2.y); a2 = __fadd_rn(a2, v2.z); a3 = __fadd_rn(a3, v2.w);
        a0 = __fadd_rn(a0, v3.x); a1 = __fadd_rn(a1, v3.y); a2 = __fadd_rn(a2, v3.z); a3 = __fadd_rn(a3, v3.w);
        a0 = __fadd_rn(a0, v4.x); a1 = __fadd_rn(a1, v4.y); a2 = __fadd_rn(a2, v4.z); a3 = __fadd_rn(a3, v4.w);
        a0 = __fadd_rn(a0, v5.x); a1 = __fadd_rn(a1, v5.y); a2 = __fadd_rn(a2, v5.z); a3 = __fadd_rn(a3, v5.w);
        a0 = __fadd_rn(a0, v6.x); a1 = __fadd_rn(a1, v6.y); a2 = __fadd_rn(a2, v6.z); a3 = __fadd_rn(a3, v6.w);
        a0 = __fadd_rn(a0, v7.x); a1 = __fadd_rn(a1, v7.y); a2 = __fadd_rn(a2, v7.z); a3 = __fadd_rn(a3, v7.w);
    }
    for (; p < end; ++p) {
        int nb = csr_src[p];
        float4 v = *(const float4*)(X + (size_t)nb * DIM + co);
        a0 = __fadd_rn(a0, v.x); a1 = __fadd_rn(a1, v.y); a2 = __fadd_rn(a2, v.z); a3 = __fadd_rn(a3, v.w);
    }
    float4 o; o.x = a0; o.y = a1; o.z = a2; o.w = a3;
    *(float4*)(AGG + (size_t)n * DIM + co) = o;
}

// ---------------- GEMM1: h1 = relu(bn((1+eps)x + agg) @ W1 + b1)), 128x128 tile, 8x8 micro ----------------
__global__ __launch_bounds__(256) void k_gemm1(const float* __restrict__ X, const float* __restrict__ AGG,
        const float* __restrict__ epss, const float* __restrict__ Ws1, const float* __restrict__ bs1,
        const float* __restrict__ g1s, const float* __restrict__ be1s, const float* __restrict__ rm1s,
        const float* __restrict__ rv1s, int l, float* __restrict__ H1out) {
    __shared__ float As[16][132];
    __shared__ float Bs[16][132];
    const float* W1  = Ws1 + (size_t)l * DIM * H2;
    const float* b1  = bs1 + l * H2;
    const float* g1  = g1s + l * H2;
    const float* be1 = be1s + l * H2;
    const float* rm1 = rm1s + l * H2;
    const float* rv1 = rv1s + l * H2;
    const float ep = __fadd_rn(1.0f, epss[l]);
    // grid 1024 (512 M-tiles x 2 N-tiles), XCD swizzle
    int bid = blockIdx.x;
    int wg = (bid & 7) * 128 + (bid >> 3);
    const int mbase = (wg >> 1) * 128;
    const int nbase = (wg & 1) * 128;
    const int tid = threadIdx.x;
    const int srow = tid >> 1;          // 0..127
    const int sk   = (tid & 1) * 8;     // 0 or 8
    const int bk = tid >> 4;            // 0..15
    const int bcg = (tid & 15) * 4;     // 0..60
    const int ty = tid >> 4;            // 0..15
    const int tx = tid & 15;            // 0..15
    v2f acc[8][4] = {};
    for (int kt = 0; kt < DIM; kt += 16) {
        __syncthreads();
        const float* xr = X   + (size_t)(mbase + srow) * DIM + kt + sk;
        const float* ar = AGG + (size_t)(mbase + srow) * DIM + kt + sk;
        const float4 x0 = *(const float4*)(xr);
        const float4 x1 = *(const float4*)(xr + 4);
        const float4 q0 = *(const float4*)(ar);
        const float4 q1 = *(const float4*)(ar + 4);
        As[sk + 0][srow] = __fadd_rn(__fmul_rn(ep, x0.x), q0.x);
        As[sk + 1][srow] = __fadd_rn(__fmul_rn(ep, x0.y), q0.y);
        As[sk + 2][srow] = __fadd_rn(__fmul_rn(ep, x0.z), q0.z);
        As[sk + 3][srow] = __fadd_rn(__fmul_rn(ep, x0.w), q0.w);
        As[sk + 4][srow] = __fadd_rn(__fmul_rn(ep, x1.x), q1.x);
        As[sk + 5][srow] = __fadd_rn(__fmul_rn(ep, x1.y), q1.y);
        As[sk + 6][srow] = __fadd_rn(__fmul_rn(ep, x1.z), q1.z);
        As[sk + 7][srow] = __fadd_rn(__fmul_rn(ep, x1.w), q1.w);
        const float* wrow = W1 + (size_t)(kt + bk) * H2 + nbase;
        *(float4*)&Bs[bk][bcg]      = *(const float4*)(wrow + bcg);
        *(float4*)&Bs[bk][bcg + 64] = *(const float4*)(wrow + bcg + 64);
        __syncthreads();
        #pragma unroll
        for (int kk = 0; kk < 16; ++kk) {
            const float4 aA = *(const float4*)&As[kk][ty * 8];
            const float4 aB = *(const float4*)&As[kk][ty * 8 + 4];
            const float4 b0 = *(const float4*)&Bs[kk][tx * 4];
            const float4 b1v = *(const float4*)&Bs[kk][tx * 4 + 64];
            v2f b00; b00[0] = b0.x;  b00[1] = b0.y;
            v2f b01; b01[0] = b0.z;  b01[1] = b0.w;
            v2f b10; b10[0] = b1v.x; b10[1] = b1v.y;
            v2f b11; b11[0] = b1v.z; b11[1] = b1v.w;
            const float arr[8] = {aA.x, aA.y, aA.z, aA.w, aB.x, aB.y, aB.z, aB.w};
            #pragma unroll
            for (int i = 0; i < 8; ++i) {
                v2f ai; ai[0] = arr[i]; ai[1] = arr[i];
                acc[i][0] = __builtin_elementwise_fma(ai, b00, acc[i][0]);
                acc[i][1] = __builtin_elementwise_fma(ai, b01, acc[i][1]);
                acc[i][2] = __builtin_elementwise_fma(ai, b10, acc[i][2]);
                acc[i][3] = __builtin_elementwise_fma(ai, b11, acc[i][3]);
            }
        }
    }
    const int gc = nbase + tx * 4;
    float bb[8], iv[8], gg[8], rr[8], ee[8];
    #pragma unroll
    for (int j = 0; j < 8; ++j) {
        int c = (j < 4) ? (gc + j) : (gc + 60 + j);   // gc+j / gc+64+(j-4)
        bb[j] = b1[c];
        iv[j] = __fdiv_rn(1.0f, __fsqrt_rn(__fadd_rn(rv1[c], 1e-5f)));
        gg[j] = g1[c];
        rr[j] = rm1[c];
        ee[j] = be1[c];
    }
    #pragma unroll
    for (int i = 0; i < 8; ++i) {
        const int gr = mbase + ty * 8 + i;
        float cv[8] = {acc[i][0][0], acc[i][0][1], acc[i][1][0], acc[i][1][1],
                       acc[i][2][0], acc[i][2][1], acc[i][3][0], acc[i][3][1]};
        float r[8];
        #pragma unroll
        for (int j = 0; j < 8; ++j) {
            float t = __fadd_rn(cv[j], bb[j]);
            t = __fsub_rn(t, rr[j]); t = __fmul_rn(t, iv[j]);
            t = __fmul_rn(t, gg[j]); t = __fadd_rn(t, ee[j]);
            r[j] = fmaxf(t, 0.f);
        }
        float4 o0; o0.x = r[0]; o0.y = r[1]; o0.z = r[2]; o0.w = r[3];
        float4 o1; o1.x = r[4]; o1.y = r[5]; o1.z = r[6]; o1.w = r[7];
        *(float4*)(H1out + (size_t)gr * H2 + gc)      = o0;
        *(float4*)(H1out + (size_t)gr * H2 + gc + 64) = o1;
    }
}

// ---------------- GEMM2: x = relu(bn(h1 @ W2 + b2)), 128x128 tile, 8x8 micro ----------------
__global__ __launch_bounds__(256) void k_gemm2(const float* __restrict__ H1, const float* __restrict__ Ws2,
        const float* __restrict__ bs2, const float* __restrict__ gbn, const float* __restrict__ bbn,
        const float* __restrict__ rmbn, const float* __restrict__ rvbn, int l, float* __restrict__ Xout) {
    __shared__ float As[16][132];
    __shared__ float Bs[16][132];
    const float* W2 = Ws2 + (size_t)l * H2 * HID;
    const float* b2 = bs2 + l * HID;
    const float* g  = gbn + l * HID;
    const float* be = bbn + l * HID;
    const float* rm = rmbn + l * HID;
    const float* rv = rvbn + l * HID;
    // grid 512 (512 M-tiles x 1 N-tile), XCD swizzle
    int bid = blockIdx.x;
    int wg = (bid & 7) * 64 + (bid >> 3);
    const int mbase = wg * 128;
    const int nbase = 0;
    const int tid = threadIdx.x;
    const int srow = tid >> 1;
    const int sk   = (tid & 1) * 8;
    const int bk = tid >> 4;
    const int bcg = (tid & 15) * 4;
    const int ty = tid >> 4;
    const int tx = tid & 15;
    v2f acc[8][4] = {};
    for (int kt = 0; kt < H2; kt += 16) {
        __syncthreads();
        const float* hr = H1 + (size_t)(mbase + srow) * H2 + kt + sk;
        const float4 h0 = *(const float4*)(hr);
        const float4 h1v = *(const float4*)(hr + 4);
        As[sk + 0][srow] = h0.x;
        As[sk + 1][srow] = h0.y;
        As[sk + 2][srow] = h0.z;
        As[sk + 3][srow] = h0.w;
        As[sk + 4][srow] = h1v.x;
        As[sk + 5][srow] = h1v.y;
        As[sk + 6][srow] = h1v.z;
        As[sk + 7][srow] = h1v.w;
        const float* wrow = W2 + (size_t)(kt + bk) * HID + nbase;
        *(float4*)&Bs[bk][bcg]      = *(const float4*)(wrow + bcg);
        *(float4*)&Bs[bk][bcg + 64] = *(const float4*)(wrow + bcg + 64);
        __syncthreads();
        #pragma unroll
        for (int kk = 0; kk < 16; ++kk) {
            const float4 aA = *(const float4*)&As[kk][ty * 8];
            const float4 aB = *(const float4*)&As[kk][ty * 8 + 4];
            const float4 b0 = *(const float4*)&Bs[kk][tx * 4];
            const float4 b1v = *(const float4*)&Bs[kk][tx * 4 + 64];
            v2f b00; b00[0] = b0.x;  b00[1] = b0.y;
            v2f b01; b01[0] = b0.z;  b01[1] = b0.w;
            v2f b10; b10[0] = b1v.x; b10[1] = b1v.y;
            v2f b11; b11[0] = b1v.z; b11[1] = b1v.w;
            const float arr[8] = {aA.x, aA.y, aA.z, aA.w, aB.x, aB.y, aB.z, aB.w};
            #pragma unroll
            for (int i = 0; i < 8; ++i) {
                v2f ai; ai[0] = arr[i]; ai[1] = arr[i];
                acc[i][0] = __builtin_elementwise_fma(ai, b00, acc[i][0]);
                acc[i][1] = __builtin_elementwise_fma(ai, b01, acc[i][1]);
                acc[i][2] = __builtin_elementwise_fma(ai, b10, acc[i][2]);
                acc[i][3] = __builtin_elementwise_fma(ai, b11, acc[i][3]);
            }
        }
    }
    const int gc = nbase + tx * 4;
    float bb[8], iv[8], gg[8], rr[8], ee[8];
    #pragma unroll
    for (int j = 0; j < 8; ++j) {
        int c = (j < 4) ? (gc + j) : (gc + 60 + j);
        bb[j] = b2[c];
        iv[j] = __fdiv_rn(1.0f, __fsqrt_rn(__fadd_rn(rv[c], 1e-5f)));
        gg[j] = g[c];
        rr[j] = rm[c];
        ee[j] = be[c];
    }
    #pragma unroll
    for (int i = 0; i < 8; ++i) {
        const int gr = mbase + ty * 8 + i;
        float cv[8] = {acc[i][0][0], acc[i][0][1], acc[i][1][0], acc[i][1][1],
                       acc[i][2][0], acc[i][2][1], acc[i][3][0], acc[i][3][1]};
        float r[8];
        #pragma unroll
        for (int j = 0; j < 8; ++j) {
            float t = __fadd_rn(cv[j], bb[j]);
            t = __fsub_rn(t, rr[j]); t = __fmul_rn(t, iv[j]);
            t = __fmul_rn(t, gg[j]); t = __fadd_rn(t, ee[j]);
            r[j] = fmaxf(t, 0.f);
        }
        float4 o0; o0.x = r[0]; o0.y = r[1]; o0.z = r[2]; o0.w = r[3];
        float4 o1; o1.x = r[4]; o1.y = r[5]; o1.z = r[6]; o1.w = r[7];
        *(float4*)(Xout + (size_t)gr * HID + gc)      = o0;
        *(float4*)(Xout + (size_t)gr * HID + gc + 64) = o1;
    }
}

// ---------------- score: XLA fast-tanh plateau at |p| >= 7.90531110763549805 ----------------
__global__ __launch_bounds__(256) void k_score(const float* __restrict__ X, const float* __restrict__ AGG,
        const float* __restrict__ Wrel, const float* __restrict__ brel, const float* __restrict__ Wroot,
        float* __restrict__ S) {
    __shared__ float wr[128], wo[128];
    int t = threadIdx.x;
    if (t < 128) { wr[t] = Wrel[t]; wo[t] = Wroot[t]; }
    __syncthreads();
    int n = blockIdx.x * 256 + t;
    const float* a = AGG + (size_t)n * HID;
    const float* x = X + (size_t)n * HID;
    float p1 = 0.f, p2 = 0.f;
    #pragma unroll 8
    for (int k = 0; k < HID; ++k) p1 = __fmaf_rn(a[k], wr[k], p1);
    #pragma unroll 8
    for (int k = 0; k < HID; ++k) p2 = __fmaf_rn(x[k], wo[k], p2);
    float pp = __fadd_rn(__fadd_rn(p1, brel[0]), p2);
    const float PC = 7.90531110763549805f;
    float s;
    if (pp >= PC)       s = 1.0f;
    else if (pp <= -PC) s = -1.0f;
    else                s = (float)tanh((double)pp);
    S[n] = s;
}

// ---------------- SAGPool top-K on f32 score (value desc, index asc) + pool ----------------
__global__ __launch_bounds__(512) void k_pool(const float* __restrict__ X, const float* __restrict__ S,
                                              float* __restrict__ EMB, double* __restrict__ EMB64) {
    __shared__ unsigned key[512];
    __shared__ double w[512];
    __shared__ double red[4][128];
    const int b = blockIdx.x, tid = threadIdx.x;
    float v = S[b * NNODE + tid];
    unsigned u = __float_as_uint(v);
    unsigned o = (u & 0x80000000u) ? ~u : (u | 0x80000000u);
    key[tid] = o;
    __syncthreads();
    int rank = 0;
    for (int j = 0; j < NNODE; ++j) {
        unsigned kj = key[j];
        rank += (int)((kj > o) || (kj == o && j < tid));
    }
    w[tid] = (rank < KSEL) ? (double)v : 0.0;
    __syncthreads();
    const int jgrp = tid >> 7;
    const int col = tid & 127;
    double acc = 0.0;
    for (int i = jgrp; i < NNODE; i += 4) {
        acc += (double)X[((size_t)b * NNODE + i) * HID + col] * w[i];
    }
    red[jgrp][col] = acc;
    __syncthreads();
    if (jgrp == 0) {
        double e = red[0][col] + red[1][col] + red[2][col] + red[3][col];
        EMB[b * HID + col] = (float)e;
        EMB64[b * HID + col] = e;
    }
}

// ---------------- head (f64) ----------------
__global__ __launch_bounds__(128) void k_head(const double* __restrict__ EMB64,
        const float* __restrict__ W1, const float* __restrict__ b1,
        const float* __restrict__ g, const float* __restrict__ be,
        const float* __restrict__ rm, const float* __restrict__ rv,
        const float* __restrict__ W2, const float* __restrict__ b2,
        float* __restrict__ LOGITS) {
    __shared__ double e[128];
    __shared__ double h[128];
    const int b = blockIdx.x, t = threadIdx.x;
    e[t] = EMB64[b * HID + t];
    __syncthreads();
    double acc = 0.0;
    for (int k = 0; k < HID; ++k) acc += e[k] * (double)W1[k * HID + t];
    acc += (double)b1[t];
    double inv = 1.0 / sqrt((double)rv[t] + 1e-5);
    acc = (acc - (double)rm[t]) * inv * (double)g[t] + (double)be[t];
    h[t] = fmax(acc, 0.0);
    __syncthreads();
    if (t < OUTC) {
        double a2 = (double)b2[t];
        for (int k = 0; k < HID; ++k) a2 += h[k] * (double)W2[k * OUTC + t];
        LOGITS[b * OUTC + t] = (float)a2;
    }
}

extern "C" void kernel_launch(void* const* d_in, const int* in_sizes, int n_in,
                              void* d_out, int out_size, void* d_ws, size_t ws_size,
                              hipStream_t stream) {
    const float* x     = (const float*)d_in[0];
    const int*   edge  = (const int*)d_in[1];
    const int*   src   = edge;
    const int*   dst   = edge + EDGES;
    const float* epss  = (const float*)d_in[3];
    const float* Ws1   = (const float*)d_in[4];
    const float* bs1   = (const float*)d_in[5];
    const float* g1s   = (const float*)d_in[6];
    const float* be1s  = (const float*)d_in[7];
    const float* rm1s  = (const float*)d_in[8];
    const float* rv1s  = (const float*)d_in[9];
    const float* Ws2   = (const float*)d_in[10];
    const float* bs2   = (const float*)d_in[11];
    const float* gbn   = (const float*)d_in[12];
    const float* bbn   = (const float*)d_in[13];
    const float* rmbn  = (const float*)d_in[14];
    const float* rvbn  = (const float*)d_in[15];
    const float* Wrel  = (const float*)d_in[16];
    const float* brel  = (const float*)d_in[17];
    const float* Wroot = (const float*)d_in[18];
    const float* W_lin1= (const float*)d_in[19];
    const float* b_lin1= (const float*)d_in[20];
    const float* g_h   = (const float*)d_in[21];
    const float* be_h  = (const float*)d_in[22];
    const float* rm_h  = (const float*)d_in[23];
    const float* rv_h  = (const float*)d_in[24];
    const float* W_lin2= (const float*)d_in[25];
    const float* b_lin2= (const float*)d_in[26];

    char* ws = (char*)d_ws;
    float*  x_cur    = (float*) (ws);                    // 32 MB
    float*  agg      = (float*) (ws + 33554432);         // 32 MB
    float*  h1       = (float*) (ws + 67108864);         // 64 MB
    float*  s32      = (float*) (ws + 134217728);        // 256 KB
    double* emb64    = (double*)(ws + 134479872);        // 128 KB
    int*    row_start= (int*)   (ws + 134610944);        // 256 KB + 4
    int*    cursor   = (int*)   (ws + 134877184);        // 256 KB
    int*    counts   = (int*)   (ws + 135139328);        // 256 KB
    int*    csr     = (int*)    (ws + 135401472);        // 4 MB

    float* emb    = (float*)d_out;
    float* logits = (float*)d_out + BGRAPH * HID;

    // ---- CSR (by dst): counts -> scan -> fill(eids) -> LDS row sort (edge order) ----
    hipMemsetAsync(counts, 0, NT_ * sizeof(int), stream);
    k_count<<<EDGES / 256, 256, 0, stream>>>(dst, counts);
    k_scan<<<1, 1024, 0, stream>>>(counts, row_start, cursor);
    k_fill<<<EDGES / 256, 256, 0, stream>>>(dst, cursor, csr);
    k_sortrows<<<NT_ / 256, 256, 0, stream>>>(src, row_start, csr);

    // ---- layer 0 ----
    k_agg<<<NT_ / 8, 256, 0, stream>>>(x, row_start, csr, agg);
    k_gemm1<<<1024, 256, 0, stream>>>(x, agg, epss, Ws1, bs1, g1s, be1s, rm1s, rv1s, 0, h1);
    k_gemm2<<<512, 256, 0, stream>>>(h1, Ws2, bs2, gbn, bbn, rmbn, rvbn, 0, x_cur);
    // ---- layer 1 ----
    k_agg<<<NT_ / 8, 256, 0, stream>>>(x_cur, row_start, csr, agg);
    k_gemm1<<<1024, 256, 0, stream>>>(x_cur, agg, epss, Ws1, bs1, g1s, be1s, rm1s, rv1s, 1, h1);
    k_gemm2<<<512, 256, 0, stream>>>(h1, Ws2, bs2, gbn, bbn, rmbn, rvbn, 1, x_cur);
    // ---- scoring + pool + head ----
    k_agg<<<NT_ / 8, 256, 0, stream>>>(x_cur, row_start, csr, agg);
    k_score<<<NT_ / 256, 256, 0, stream>>>(x_cur, agg, Wrel, brel, Wroot, s32);
    k_pool<<<BGRAPH, 512, 0, stream>>>(x_cur, s32, emb, emb64);
    k_head<<<BGRAPH, 128, 0, stream>>>(emb64, W_lin1, b_lin1, g_h, be_h, rm_h, rv_h, W_lin2, b_lin2, logits);
}

// Round 9
// 544.142 us; speedup vs baseline: 1.4820x; 1.0052x over previous
//
#include <hip/hip_runtime.h>
#include <hip/hip_bf16.h>
#include <stdint.h>
#include <math.h>

#define NT_ 65536
#define BGRAPH 128
#define NNODE 512
#define DIM 128
#define HID 128
#define H2 256
#define EDGES 1048576
#define KSEL 256
#define OUTC 10
#define SCAP 48

typedef float v2f __attribute__((ext_vector_type(2)));

// ---------------- CSR build ----------------
__global__ void k_count(const int* __restrict__ dst, int* __restrict__ counts) {
    int e = blockIdx.x * blockDim.x + threadIdx.x;
    if (e < EDGES) atomicAdd(&counts[dst[e]], 1);
}

__global__ __launch_bounds__(1024) void k_scan(const int* __restrict__ counts,
                                               int* __restrict__ row_start,
                                               int* __restrict__ cursor) {
    __shared__ int part[1024];
    int t = threadIdx.x;
    int base = t * 64;
    int s = 0;
    #pragma unroll
    for (int i = 0; i < 64; ++i) s += counts[base + i];
    part[t] = s;
    __syncthreads();
    for (int off = 1; off < 1024; off <<= 1) {
        int v = (t >= off) ? part[t - off] : 0;
        __syncthreads();
        part[t] += v;
        __syncthreads();
    }
    int run = part[t] - s;
    for (int i = 0; i < 64; ++i) {
        row_start[base + i] = run;
        cursor[base + i] = run;
        run += counts[base + i];
    }
    if (t == 1023) row_start[NT_] = part[1023];
}

__global__ void k_fill(const int* __restrict__ dst,
                       int* __restrict__ cursor, int* __restrict__ csr) {
    int e = blockIdx.x * blockDim.x + threadIdx.x;
    if (e < EDGES) {
        int d = dst[e];
        int pos = atomicAdd(&cursor[d], 1);
        csr[pos] = e;
    }
}

// sort each row's edge-ids ascending in LDS (restore edge order), then map eid->src
__global__ __launch_bounds__(256) void k_sortrows(const int* __restrict__ src,
                                                  const int* __restrict__ row_start,
                                                  int* __restrict__ csr) {
    __shared__ int buf[256 * SCAP];   // 48 KB
    int t = threadIdx.x;
    int n = blockIdx.x * 256 + t;
    int beg = row_start[n], end = row_start[n + 1];
    int d = end - beg;
    int* my = &buf[t * SCAP];
    if (d <= SCAP) {
        for (int i = 0; i < d; ++i) my[i] = csr[beg + i];
        for (int i = 1; i < d; ++i) {
            int key = my[i];
            int j = i - 1;
            while (j >= 0 && my[j] > key) { my[j + 1] = my[j]; --j; }
            my[j + 1] = key;
        }
        for (int i = 0; i < d; ++i) csr[beg + i] = src[my[i]];
    } else {
        for (int i = beg + 1; i < end; ++i) {
            int key = csr[i];
            int j = i - 1;
            while (j >= beg && csr[j] > key) { csr[j + 1] = csr[j]; --j; }
            csr[j + 1] = key;
        }
        for (int p = beg; p < end; ++p) csr[p] = src[csr[p]];
    }
}

// ---------------- aggregation: 2 nodes/wave, float4 lanes, edge-order f32 chain ----------------
__global__ __launch_bounds__(256) void k_agg(const float* __restrict__ X,
                                             const int* __restrict__ row_start,
                                             const int* __restrict__ csr_src,
                                             float* __restrict__ AGG) {
    int bid = blockIdx.x;
    int wg = (bid & 7) * 1024 + (bid >> 3);
    int wave = threadIdx.x >> 6;
    int lane = threadIdx.x & 63;
    int half = lane >> 5;
    int l32 = lane & 31;
    int n = wg * 8 + wave * 2 + half;
    int beg = row_start[n], end = row_start[n + 1];
    const size_t co = (size_t)(l32 * 4);
    float a0 = 0.f, a1 = 0.f, a2 = 0.f, a3 = 0.f;
    int p = beg;
    for (; p + 8 <= end; p += 8) {
        int n0 = csr_src[p+0], n1 = csr_src[p+1], n2 = csr_src[p+2], n3 = csr_src[p+3];
        int n4 = csr_src[p+4], n5 = csr_src[p+5], n6 = csr_src[p+6], n7 = csr_src[p+7];
        float4 v0 = *(const float4*)(X + (size_t)n0 * DIM + co);
        float4 v1 = *(const float4*)(X + (size_t)n1 * DIM + co);
        float4 v2 = *(const float4*)(X + (size_t)n2 * DIM + co);
        float4 v3 = *(const float4*)(X + (size_t)n3 * DIM + co);
        float4 v4 = *(const float4*)(X + (size_t)n4 * DIM + co);
        float4 v5 = *(const float4*)(X + (size_t)n5 * DIM + co);
        float4 v6 = *(const float4*)(X + (size_t)n6 * DIM + co);
        float4 v7 = *(const float4*)(X + (size_t)n7 * DIM + co);
        a0 = __fadd_rn(a0, v0.x); a1 = __fadd_rn(a1, v0.y); a2 = __fadd_rn(a2, v0.z); a3 = __fadd_rn(a3, v0.w);
        a0 = __fadd_rn(a0, v1.x); a1 = __fadd_rn(a1, v1.y); a2 = __fadd_rn(a2, v1.z); a3 = __fadd_rn(a3, v1.w);
        a0 = __fadd_rn(a0, v2.x); a1 = __fadd_rn(a1, v2.y); a2 = __fadd_rn(a2, v2.z); a3 = __fadd_rn(a3, v2.w);
        a0 = __fadd_rn(a0, v3.x); a1 = __fadd_rn(a1, v3.y); a2 = __fadd_rn(a2, v3.z); a3 = __fadd_rn(a3, v3.w);
        a0 = __fadd_rn(a0, v4.x); a1 = __fadd_rn(a1, v4.y); a2 = __fadd_rn(a2, v4.z); a3 = __fadd_rn(a3, v4.w);
        a0 = __fadd_rn(a0, v5.x); a1 = __fadd_rn(a1, v5.y); a2 = __fadd_rn(a2, v5.z); a3 = __fadd_rn(a3, v5.w);
        a0 = __fadd_rn(a0, v6.x); a1 = __fadd_rn(a1, v6.y); a2 = __fadd_rn(a2, v6.z); a3 = __fadd_rn(a3, v6.w);
        a0 = __fadd_rn(a0, v7.x); a1 = __fadd_rn(a1, v7.y); a2 = __fadd_rn(a2, v7.z); a3 = __fadd_rn(a3, v7.w);
    }
    for (; p < end; ++p) {
        int nb = csr_src[p];
        float4 v = *(const float4*)(X + (size_t)nb * DIM + co);
        a0 = __fadd_rn(a0, v.x); a1 = __fadd_rn(a1, v.y); a2 = __fadd_rn(a2, v.z); a3 = __fadd_rn(a3, v.w);
    }
    float4 o; o.x = a0; o.y = a1; o.z = a2; o.w = a3;
    *(float4*)(AGG + (size_t)n * DIM + co) = o;
}

// ---------------- GEMM1: 128x128 tile, BK=32, 8x8 micro ----------------
__global__ __launch_bounds__(256) void k_gemm1(const float* __restrict__ X, const float* __restrict__ AGG,
        const float* __restrict__ epss, const float* __restrict__ Ws1, const float* __restrict__ bs1,
        const float* __restrict__ g1s, const float* __restrict__ be1s, const float* __restrict__ rm1s,
        const float* __restrict__ rv1s, int l, float* __restrict__ H1out) {
    __shared__ float As[32][132];
    __shared__ float Bs[32][132];
    const float* W1  = Ws1 + (size_t)l * DIM * H2;
    const float* b1  = bs1 + l * H2;
    const float* g1  = g1s + l * H2;
    const float* be1 = be1s + l * H2;
    const float* rm1 = rm1s + l * H2;
    const float* rv1 = rv1s + l * H2;
    const float ep = __fadd_rn(1.0f, epss[l]);
    int bid = blockIdx.x;
    int wg = (bid & 7) * 128 + (bid >> 3);
    const int mbase = (wg >> 1) * 128;
    const int nbase = (wg & 1) * 128;
    const int tid = threadIdx.x;
    const int srow = tid >> 1;          // 0..127
    const int sk   = (tid & 1) * 16;    // 0 or 16
    const int bk   = tid >> 3;          // 0..31
    const int bcg  = (tid & 7) * 16;    // 0..112
    const int ty = tid >> 4;            // 0..15
    const int tx = tid & 15;            // 0..15
    v2f acc[8][4] = {};
    for (int kt = 0; kt < DIM; kt += 32) {
        __syncthreads();
        const float* xr = X   + (size_t)(mbase + srow) * DIM + kt + sk;
        const float* ar = AGG + (size_t)(mbase + srow) * DIM + kt + sk;
        #pragma unroll
        for (int q = 0; q < 4; ++q) {
            const float4 xv = *(const float4*)(xr + q * 4);
            const float4 qv = *(const float4*)(ar + q * 4);
            As[sk + q*4 + 0][srow] = __fadd_rn(__fmul_rn(ep, xv.x), qv.x);
            As[sk + q*4 + 1][srow] = __fadd_rn(__fmul_rn(ep, xv.y), qv.y);
            As[sk + q*4 + 2][srow] = __fadd_rn(__fmul_rn(ep, xv.z), qv.z);
            As[sk + q*4 + 3][srow] = __fadd_rn(__fmul_rn(ep, xv.w), qv.w);
        }
        const float* wrow = W1 + (size_t)(kt + bk) * H2 + nbase + bcg;
        #pragma unroll
        for (int q = 0; q < 4; ++q) {
            *(float4*)&Bs[bk][bcg + q * 4] = *(const float4*)(wrow + q * 4);
        }
        __syncthreads();
        #pragma unroll
        for (int kk = 0; kk < 32; ++kk) {
            const float4 aA = *(const float4*)&As[kk][ty * 8];
            const float4 aB = *(const float4*)&As[kk][ty * 8 + 4];
            const float4 b0 = *(const float4*)&Bs[kk][tx * 4];
            const float4 b1v = *(const float4*)&Bs[kk][tx * 4 + 64];
            v2f b00; b00[0] = b0.x;  b00[1] = b0.y;
            v2f b01; b01[0] = b0.z;  b01[1] = b0.w;
            v2f b10; b10[0] = b1v.x; b10[1] = b1v.y;
            v2f b11; b11[0] = b1v.z; b11[1] = b1v.w;
            const float arr[8] = {aA.x, aA.y, aA.z, aA.w, aB.x, aB.y, aB.z, aB.w};
            #pragma unroll
            for (int i = 0; i < 8; ++i) {
                v2f ai; ai[0] = arr[i]; ai[1] = arr[i];
                acc[i][0] = __builtin_elementwise_fma(ai, b00, acc[i][0]);
                acc[i][1] = __builtin_elementwise_fma(ai, b01, acc[i][1]);
                acc[i][2] = __builtin_elementwise_fma(ai, b10, acc[i][2]);
                acc[i][3] = __builtin_elementwise_fma(ai, b11, acc[i][3]);
            }
        }
    }
    const int gc = nbase + tx * 4;
    float bb[8], iv[8], gg[8], rr[8], ee[8];
    #pragma unroll
    for (int j = 0; j < 8; ++j) {
        int c = (j < 4) ? (gc + j) : (gc + 60 + j);
        bb[j] = b1[c];
        iv[j] = __fdiv_rn(1.0f, __fsqrt_rn(__fadd_rn(rv1[c], 1e-5f)));
        gg[j] = g1[c];
        rr[j] = rm1[c];
        ee[j] = be1[c];
    }
    #pragma unroll
    for (int i = 0; i < 8; ++i) {
        const int gr = mbase + ty * 8 + i;
        float cv[8] = {acc[i][0][0], acc[i][0][1], acc[i][1][0], acc[i][1][1],
                       acc[i][2][0], acc[i][2][1], acc[i][3][0], acc[i][3][1]};
        float r[8];
        #pragma unroll
        for (int j = 0; j < 8; ++j) {
            float t = __fadd_rn(cv[j], bb[j]);
            t = __fsub_rn(t, rr[j]); t = __fmul_rn(t, iv[j]);
            t = __fmul_rn(t, gg[j]); t = __fadd_rn(t, ee[j]);
            r[j] = fmaxf(t, 0.f);
        }
        float4 o0; o0.x = r[0]; o0.y = r[1]; o0.z = r[2]; o0.w = r[3];
        float4 o1; o1.x = r[4]; o1.y = r[5]; o1.z = r[6]; o1.w = r[7];
        *(float4*)(H1out + (size_t)gr * H2 + gc)      = o0;
        *(float4*)(H1out + (size_t)gr * H2 + gc + 64) = o1;
    }
}

// ---------------- GEMM2: 128x128 tile, BK=32, 8x8 micro ----------------
__global__ __launch_bounds__(256) void k_gemm2(const float* __restrict__ H1, const float* __restrict__ Ws2,
        const float* __restrict__ bs2, const float* __restrict__ gbn, const float* __restrict__ bbn,
        const float* __restrict__ rmbn, const float* __restrict__ rvbn, int l, float* __restrict__ Xout) {
    __shared__ float As[32][132];
    __shared__ float Bs[32][132];
    const float* W2 = Ws2 + (size_t)l * H2 * HID;
    const float* b2 = bs2 + l * HID;
    const float* g  = gbn + l * HID;
    const float* be = bbn + l * HID;
    const float* rm = rmbn + l * HID;
    const float* rv = rvbn + l * HID;
    int bid = blockIdx.x;
    int wg = (bid & 7) * 64 + (bid >> 3);
    const int mbase = wg * 128;
    const int tid = threadIdx.x;
    const int srow = tid >> 1;
    const int sk   = (tid & 1) * 16;
    const int bk   = tid >> 3;          // 0..31
    const int bcg  = (tid & 7) * 16;    // 0..112
    const int ty = tid >> 4;
    const int tx = tid & 15;
    v2f acc[8][4] = {};
    for (int kt = 0; kt < H2; kt += 32) {
        __syncthreads();
        const float* hr = H1 + (size_t)(mbase + srow) * H2 + kt + sk;
        #pragma unroll
        for (int q = 0; q < 4; ++q) {
            const float4 hv = *(const float4*)(hr + q * 4);
            As[sk + q*4 + 0][srow] = hv.x;
            As[sk + q*4 + 1][srow] = hv.y;
            As[sk + q*4 + 2][srow] = hv.z;
            As[sk + q*4 + 3][srow] = hv.w;
        }
        const float* wrow = W2 + (size_t)(kt + bk) * HID + bcg;
        #pragma unroll
        for (int q = 0; q < 4; ++q) {
            *(float4*)&Bs[bk][bcg + q * 4] = *(const float4*)(wrow + q * 4);
        }
        __syncthreads();
        #pragma unroll
        for (int kk = 0; kk < 32; ++kk) {
            const float4 aA = *(const float4*)&As[kk][ty * 8];
            const float4 aB = *(const float4*)&As[kk][ty * 8 + 4];
            const float4 b0 = *(const float4*)&Bs[kk][tx * 4];
            const float4 b1v = *(const float4*)&Bs[kk][tx * 4 + 64];
            v2f b00; b00[0] = b0.x;  b00[1] = b0.y;
            v2f b01; b01[0] = b0.z;  b01[1] = b0.w;
            v2f b10; b10[0] = b1v.x; b10[1] = b1v.y;
            v2f b11; b11[0] = b1v.z; b11[1] = b1v.w;
            const float arr[8] = {aA.x, aA.y, aA.z, aA.w, aB.x, aB.y, aB.z, aB.w};
            #pragma unroll
            for (int i = 0; i < 8; ++i) {
                v2f ai; ai[0] = arr[i]; ai[1] = arr[i];
                acc[i][0] = __builtin_elementwise_fma(ai, b00, acc[i][0]);
                acc[i][1] = __builtin_elementwise_fma(ai, b01, acc[i][1]);
                acc[i][2] = __builtin_elementwise_fma(ai, b10, acc[i][2]);
                acc[i][3] = __builtin_elementwise_fma(ai, b11, acc[i][3]);
            }
        }
    }
    const int gc = tx * 4;
    float bb[8], iv[8], gg[8], rr[8], ee[8];
    #pragma unroll
    for (int j = 0; j < 8; ++j) {
        int c = (j < 4) ? (gc + j) : (gc + 60 + j);
        bb[j] = b2[c];
        iv[j] = __fdiv_rn(1.0f, __fsqrt_rn(__fadd_rn(rv[c], 1e-5f)));
        gg[j] = g[c];
        rr[j] = rm[c];
        ee[j] = be[c];
    }
    #pragma unroll
    for (int i = 0; i < 8; ++i) {
        const int gr = mbase + ty * 8 + i;
        float cv[8] = {acc[i][0][0], acc[i][0][1], acc[i][1][0], acc[i][1][1],
                       acc[i][2][0], acc[i][2][1], acc[i][3][0], acc[i][3][1]};
        float r[8];
        #pragma unroll
        for (int j = 0; j < 8; ++j) {
            float t = __fadd_rn(cv[j], bb[j]);
            t = __fsub_rn(t, rr[j]); t = __fmul_rn(t, iv[j]);
            t = __fmul_rn(t, gg[j]); t = __fadd_rn(t, ee[j]);
            r[j] = fmaxf(t, 0.f);
        }
        float4 o0; o0.x = r[0]; o0.y = r[1]; o0.z = r[2]; o0.w = r[3];
        float4 o1; o1.x = r[4]; o1.y = r[5]; o1.z = r[6]; o1.w = r[7];
        *(float4*)(Xout + (size_t)gr * HID + gc)      = o0;
        *(float4*)(Xout + (size_t)gr * HID + gc + 64) = o1;
    }
}

// ---------------- score: XLA fast-tanh plateau at |p| >= 7.90531110763549805 ----------------
__global__ __launch_bounds__(256) void k_score(const float* __restrict__ X, const float* __restrict__ AGG,
        const float* __restrict__ Wrel, const float* __restrict__ brel, const float* __restrict__ Wroot,
        float* __restrict__ S) {
    __shared__ float wr[128], wo[128];
    int t = threadIdx.x;
    if (t < 128) { wr[t] = Wrel[t]; wo[t] = Wroot[t]; }
    __syncthreads();
    int n = blockIdx.x * 256 + t;
    const float* a = AGG + (size_t)n * HID;
    const float* x = X + (size_t)n * HID;
    float p1 = 0.f, p2 = 0.f;
    #pragma unroll 8
    for (int k = 0; k < HID; ++k) p1 = __fmaf_rn(a[k], wr[k], p1);
    #pragma unroll 8
    for (int k = 0; k < HID; ++k) p2 = __fmaf_rn(x[k], wo[k], p2);
    float pp = __fadd_rn(__fadd_rn(p1, brel[0]), p2);
    const float PC = 7.90531110763549805f;
    float s;
    if (pp >= PC)       s = 1.0f;
    else if (pp <= -PC) s = -1.0f;
    else                s = (float)tanh((double)pp);
    S[n] = s;
}

// ---------------- SAGPool top-K on f32 score (value desc, index asc) + pool ----------------
__global__ __launch_bounds__(512) void k_pool(const float* __restrict__ X, const float* __restrict__ S,
                                              float* __restrict__ EMB, double* __restrict__ EMB64) {
    __shared__ unsigned key[512];
    __shared__ double w[512];
    __shared__ double red[4][128];
    const int b = blockIdx.x, tid = threadIdx.x;
    float v = S[b * NNODE + tid];
    unsigned u = __float_as_uint(v);
    unsigned o = (u & 0x80000000u) ? ~u : (u | 0x80000000u);
    key[tid] = o;
    __syncthreads();
    int rank = 0;
    for (int j = 0; j < NNODE; ++j) {
        unsigned kj = key[j];
        rank += (int)((kj > o) || (kj == o && j < tid));
    }
    w[tid] = (rank < KSEL) ? (double)v : 0.0;
    __syncthreads();
    const int jgrp = tid >> 7;
    const int col = tid & 127;
    double acc = 0.0;
    for (int i = jgrp; i < NNODE; i += 4) {
        acc += (double)X[((size_t)b * NNODE + i) * HID + col] * w[i];
    }
    red[jgrp][col] = acc;
    __syncthreads();
    if (jgrp == 0) {
        double e = red[0][col] + red[1][col] + red[2][col] + red[3][col];
        EMB[b * HID + col] = (float)e;
        EMB64[b * HID + col] = e;
    }
}

// ---------------- head (f64) ----------------
__global__ __launch_bounds__(128) void k_head(const double* __restrict__ EMB64,
        const float* __restrict__ W1, const float* __restrict__ b1,
        const float* __restrict__ g, const float* __restrict__ be,
        const float* __restrict__ rm, const float* __restrict__ rv,
        const float* __restrict__ W2, const float* __restrict__ b2,
        float* __restrict__ LOGITS) {
    __shared__ double e[128];
    __shared__ double h[128];
    const int b = blockIdx.x, t = threadIdx.x;
    e[t] = EMB64[b * HID + t];
    __syncthreads();
    double acc = 0.0;
    for (int k = 0; k < HID; ++k) acc += e[k] * (double)W1[k * HID + t];
    acc += (double)b1[t];
    double inv = 1.0 / sqrt((double)rv[t] + 1e-5);
    acc = (acc - (double)rm[t]) * inv * (double)g[t] + (double)be[t];
    h[t] = fmax(acc, 0.0);
    __syncthreads();
    if (t < OUTC) {
        double a2 = (double)b2[t];
        for (int k = 0; k < HID; ++k) a2 += h[k] * (double)W2[k * OUTC + t];
        LOGITS[b * OUTC + t] = (float)a2;
    }
}

extern "C" void kernel_launch(void* const* d_in, const int* in_sizes, int n_in,
                              void* d_out, int out_size, void* d_ws, size_t ws_size,
                              hipStream_t stream) {
    const float* x     = (const float*)d_in[0];
    const int*   edge  = (const int*)d_in[1];
    const int*   src   = edge;
    const int*   dst   = edge + EDGES;
    const float* epss  = (const float*)d_in[3];
    const float* Ws1   = (const float*)d_in[4];
    const float* bs1   = (const float*)d_in[5];
    const float* g1s   = (const float*)d_in[6];
    const float* be1s  = (const float*)d_in[7];
    const float* rm1s  = (const float*)d_in[8];
    const float* rv1s  = (const float*)d_in[9];
    const float* Ws2   = (const float*)d_in[10];
    const float* bs2   = (const float*)d_in[11];
    const float* gbn   = (const float*)d_in[12];
    const float* bbn   = (const float*)d_in[13];
    const float* rmbn  = (const float*)d_in[14];
    const float* rvbn  = (const float*)d_in[15];
    const float* Wrel  = (const float*)d_in[16];
    const float* brel  = (const float*)d_in[17];
    const float* Wroot = (const float*)d_in[18];
    const float* W_lin1= (const float*)d_in[19];
    const float* b_lin1= (const float*)d_in[20];
    const float* g_h   = (const float*)d_in[21];
    const float* be_h  = (const float*)d_in[22];
    const float* rm_h  = (const float*)d_in[23];
    const float* rv_h  = (const float*)d_in[24];
    const float* W_lin2= (const float*)d_in[25];
    const float* b_lin2= (const float*)d_in[26];

    char* ws = (char*)d_ws;
    float*  x_cur    = (float*) (ws);                    // 32 MB
    float*  agg      = (float*) (ws + 33554432);         // 32 MB
    float*  h1       = (float*) (ws + 67108864);         // 64 MB
    float*  s32      = (float*) (ws + 134217728);        // 256 KB
    double* emb64    = (double*)(ws + 134479872);        // 128 KB
    int*    row_start= (int*)   (ws + 134610944);        // 256 KB + 4
    int*    cursor   = (int*)   (ws + 134877184);        // 256 KB
    int*    counts   = (int*)   (ws + 135139328);        // 256 KB
    int*    csr     = (int*)    (ws + 135401472);        // 4 MB

    float* emb    = (float*)d_out;
    float* logits = (float*)d_out + BGRAPH * HID;

    // ---- CSR (by dst): counts -> scan -> fill(eids) -> LDS row sort (edge order) ----
    hipMemsetAsync(counts, 0, NT_ * sizeof(int), stream);
    k_count<<<EDGES / 256, 256, 0, stream>>>(dst, counts);
    k_scan<<<1, 1024, 0, stream>>>(counts, row_start, cursor);
    k_fill<<<EDGES / 256, 256, 0, stream>>>(dst, cursor, csr);
    k_sortrows<<<NT_ / 256, 256, 0, stream>>>(src, row_start, csr);

    // ---- layer 0 ----
    k_agg<<<NT_ / 8, 256, 0, stream>>>(x, row_start, csr, agg);
    k_gemm1<<<1024, 256, 0, stream>>>(x, agg, epss, Ws1, bs1, g1s, be1s, rm1s, rv1s, 0, h1);
    k_gemm2<<<512, 256, 0, stream>>>(h1, Ws2, bs2, gbn, bbn, rmbn, rvbn, 0, x_cur);
    // ---- layer 1 ----
    k_agg<<<NT_ / 8, 256, 0, stream>>>(x_cur, row_start, csr, agg);
    k_gemm1<<<1024, 256, 0, stream>>>(x_cur, agg, epss, Ws1, bs1, g1s, be1s, rm1s, rv1s, 1, h1);
    k_gemm2<<<512, 256, 0, stream>>>(h1, Ws2, bs2, gbn, bbn, rmbn, rvbn, 1, x_cur);
    // ---- scoring + pool + head ----
    k_agg<<<NT_ / 8, 256, 0, stream>>>(x_cur, row_start, csr, agg);
    k_score<<<NT_ / 256, 256, 0, stream>>>(x_cur, agg, Wrel, brel, Wroot, s32);
    k_pool<<<BGRAPH, 512, 0, stream>>>(x_cur, s32, emb, emb64);
    k_head<<<BGRAPH, 128, 0, stream>>>(emb64, W_lin1, b_lin1, g_h, be_h, rm_h, rv_h, W_lin2, b_lin2, logits);
}

// Round 10
// 522.168 us; speedup vs baseline: 1.5444x; 1.0421x over previous
//
#include <hip/hip_runtime.h>
#include <hip/hip_bf16.h>
#include <stdint.h>
#include <math.h>

#define NT_ 65536
#define BGRAPH 128
#define NNODE 512
#define DIM 128
#define HID 128
#define H2 256
#define EDGES 1048576
#define KSEL 256
#define OUTC 10
#define SCAP 48

typedef float v2f __attribute__((ext_vector_type(2)));

// ---------------- CSR build ----------------
__global__ void k_count(const int* __restrict__ dst, int* __restrict__ counts) {
    int e = blockIdx.x * blockDim.x + threadIdx.x;
    if (e < EDGES) atomicAdd(&counts[dst[e]], 1);
}

__global__ __launch_bounds__(1024) void k_scan(const int* __restrict__ counts,
                                               int* __restrict__ row_start,
                                               int* __restrict__ cursor) {
    __shared__ int part[1024];
    int t = threadIdx.x;
    int base = t * 64;
    int s = 0;
    #pragma unroll
    for (int i = 0; i < 64; ++i) s += counts[base + i];
    part[t] = s;
    __syncthreads();
    for (int off = 1; off < 1024; off <<= 1) {
        int v = (t >= off) ? part[t - off] : 0;
        __syncthreads();
        part[t] += v;
        __syncthreads();
    }
    int run = part[t] - s;
    for (int i = 0; i < 64; ++i) {
        row_start[base + i] = run;
        cursor[base + i] = run;
        run += counts[base + i];
    }
    if (t == 1023) row_start[NT_] = part[1023];
}

__global__ void k_fill(const int* __restrict__ dst,
                       int* __restrict__ cursor, int* __restrict__ csr) {
    int e = blockIdx.x * blockDim.x + threadIdx.x;
    if (e < EDGES) {
        int d = dst[e];
        int pos = atomicAdd(&cursor[d], 1);
        csr[pos] = e;
    }
}

// sort each row's edge-ids ascending in LDS (restore edge order), then map eid->src
__global__ __launch_bounds__(256) void k_sortrows(const int* __restrict__ src,
                                                  const int* __restrict__ row_start,
                                                  int* __restrict__ csr) {
    __shared__ int buf[256 * SCAP];   // 48 KB
    int t = threadIdx.x;
    int n = blockIdx.x * 256 + t;
    int beg = row_start[n], end = row_start[n + 1];
    int d = end - beg;
    int* my = &buf[t * SCAP];
    if (d <= SCAP) {
        for (int i = 0; i < d; ++i) my[i] = csr[beg + i];
        for (int i = 1; i < d; ++i) {
            int key = my[i];
            int j = i - 1;
            while (j >= 0 && my[j] > key) { my[j + 1] = my[j]; --j; }
            my[j + 1] = key;
        }
        for (int i = 0; i < d; ++i) csr[beg + i] = src[my[i]];
    } else {
        for (int i = beg + 1; i < end; ++i) {
            int key = csr[i];
            int j = i - 1;
            while (j >= beg && csr[j] > key) { csr[j + 1] = csr[j]; --j; }
            csr[j + 1] = key;
        }
        for (int p = beg; p < end; ++p) csr[p] = src[csr[p]];
    }
}

// ---------------- aggregation: 2 nodes/wave, float4 lanes, edge-order f32 chain ----------------
__global__ __launch_bounds__(256) void k_agg(const float* __restrict__ X,
                                             const int* __restrict__ row_start,
                                             const int* __restrict__ csr_src,
                                             float* __restrict__ AGG) {
    int bid = blockIdx.x;
    int wg = (bid & 7) * 1024 + (bid >> 3);
    int wave = threadIdx.x >> 6;
    int lane = threadIdx.x & 63;
    int half = lane >> 5;
    int l32 = lane & 31;
    int n = wg * 8 + wave * 2 + half;
    int beg = row_start[n], end = row_start[n + 1];
    const size_t co = (size_t)(l32 * 4);
    float a0 = 0.f, a1 = 0.f, a2 = 0.f, a3 = 0.f;
    int p = beg;
    for (; p + 8 <= end; p += 8) {
        int n0 = csr_src[p+0], n1 = csr_src[p+1], n2 = csr_src[p+2], n3 = csr_src[p+3];
        int n4 = csr_src[p+4], n5 = csr_src[p+5], n6 = csr_src[p+6], n7 = csr_src[p+7];
        float4 v0 = *(const float4*)(X + (size_t)n0 * DIM + co);
        float4 v1 = *(const float4*)(X + (size_t)n1 * DIM + co);
        float4 v2 = *(const float4*)(X + (size_t)n2 * DIM + co);
        float4 v3 = *(const float4*)(X + (size_t)n3 * DIM + co);
        float4 v4 = *(const float4*)(X + (size_t)n4 * DIM + co);
        float4 v5 = *(const float4*)(X + (size_t)n5 * DIM + co);
        float4 v6 = *(const float4*)(X + (size_t)n6 * DIM + co);
        float4 v7 = *(const float4*)(X + (size_t)n7 * DIM + co);
        a0 = __fadd_rn(a0, v0.x); a1 = __fadd_rn(a1, v0.y); a2 = __fadd_rn(a2, v0.z); a3 = __fadd_rn(a3, v0.w);
        a0 = __fadd_rn(a0, v1.x); a1 = __fadd_rn(a1, v1.y); a2 = __fadd_rn(a2, v1.z); a3 = __fadd_rn(a3, v1.w);
        a0 = __fadd_rn(a0, v2.x); a1 = __fadd_rn(a1, v2.y); a2 = __fadd_rn(a2, v2.z); a3 = __fadd_rn(a3, v2.w);
        a0 = __fadd_rn(a0, v3.x); a1 = __fadd_rn(a1, v3.y); a2 = __fadd_rn(a2, v3.z); a3 = __fadd_rn(a3, v3.w);
        a0 = __fadd_rn(a0, v4.x); a1 = __fadd_rn(a1, v4.y); a2 = __fadd_rn(a2, v4.z); a3 = __fadd_rn(a3, v4.w);
        a0 = __fadd_rn(a0, v5.x); a1 = __fadd_rn(a1, v5.y); a2 = __fadd_rn(a2, v5.z); a3 = __fadd_rn(a3, v5.w);
        a0 = __fadd_rn(a0, v6.x); a1 = __fadd_rn(a1, v6.y); a2 = __fadd_rn(a2, v6.z); a3 = __fadd_rn(a3, v6.w);
        a0 = __fadd_rn(a0, v7.x); a1 = __fadd_rn(a1, v7.y); a2 = __fadd_rn(a2, v7.z); a3 = __fadd_rn(a3, v7.w);
    }
    for (; p < end; ++p) {
        int nb = csr_src[p];
        float4 v = *(const float4*)(X + (size_t)nb * DIM + co);
        a0 = __fadd_rn(a0, v.x); a1 = __fadd_rn(a1, v.y); a2 = __fadd_rn(a2, v.z); a3 = __fadd_rn(a3, v.w);
    }
    float4 o; o.x = a0; o.y = a1; o.z = a2; o.w = a3;
    *(float4*)(AGG + (size_t)n * DIM + co) = o;
}

// ---------------- GEMM1: 128x128 tile, BK=16, dbuf ping-pong, 1 barrier/iter ----------------
__global__ __launch_bounds__(256) void k_gemm1(const float* __restrict__ X, const float* __restrict__ AGG,
        const float* __restrict__ epss, const float* __restrict__ Ws1, const float* __restrict__ bs1,
        const float* __restrict__ g1s, const float* __restrict__ be1s, const float* __restrict__ rm1s,
        const float* __restrict__ rv1s, int l, float* __restrict__ H1out) {
    __shared__ float As[2][16][132];
    __shared__ float Bs[2][16][132];
    const float* W1  = Ws1 + (size_t)l * DIM * H2;
    const float* b1  = bs1 + l * H2;
    const float* g1  = g1s + l * H2;
    const float* be1 = be1s + l * H2;
    const float* rm1 = rm1s + l * H2;
    const float* rv1 = rv1s + l * H2;
    const float ep = __fadd_rn(1.0f, epss[l]);
    int bid = blockIdx.x;
    int wg = (bid & 7) * 128 + (bid >> 3);
    const int mbase = (wg >> 1) * 128;
    const int nbase = (wg & 1) * 128;
    const int tid = threadIdx.x;
    const int srow = tid >> 1;          // 0..127
    const int sk   = (tid & 1) * 8;     // 0 or 8
    const int bk   = tid >> 4;          // 0..15
    const int bc   = (tid & 15) * 4;    // 0..60
    const int ty = tid >> 4;
    const int tx = tid & 15;
    v2f acc[8][4] = {};
    const float* xr = X   + (size_t)(mbase + srow) * DIM + sk;
    const float* ar = AGG + (size_t)(mbase + srow) * DIM + sk;
    float4 px0, px1, pq0, pq1, pw0, pw1;
    // prologue: kt=0 -> buf 0
    px0 = *(const float4*)(xr);     px1 = *(const float4*)(xr + 4);
    pq0 = *(const float4*)(ar);     pq1 = *(const float4*)(ar + 4);
    {
        const float* wrow = W1 + (size_t)bk * H2 + nbase;
        pw0 = *(const float4*)(wrow + bc); pw1 = *(const float4*)(wrow + bc + 64);
    }
    As[0][sk + 0][srow] = __fadd_rn(__fmul_rn(ep, px0.x), pq0.x);
    As[0][sk + 1][srow] = __fadd_rn(__fmul_rn(ep, px0.y), pq0.y);
    As[0][sk + 2][srow] = __fadd_rn(__fmul_rn(ep, px0.z), pq0.z);
    As[0][sk + 3][srow] = __fadd_rn(__fmul_rn(ep, px0.w), pq0.w);
    As[0][sk + 4][srow] = __fadd_rn(__fmul_rn(ep, px1.x), pq1.x);
    As[0][sk + 5][srow] = __fadd_rn(__fmul_rn(ep, px1.y), pq1.y);
    As[0][sk + 6][srow] = __fadd_rn(__fmul_rn(ep, px1.z), pq1.z);
    As[0][sk + 7][srow] = __fadd_rn(__fmul_rn(ep, px1.w), pq1.w);
    *(float4*)&Bs[0][bk][bc]      = pw0;
    *(float4*)&Bs[0][bk][bc + 64] = pw1;
    __syncthreads();
    int cur = 0;
    for (int kt = 0; kt < DIM; kt += 16) {
        const int nxt = kt + 16;
        if (nxt < DIM) {
            px0 = *(const float4*)(xr + nxt);     px1 = *(const float4*)(xr + nxt + 4);
            pq0 = *(const float4*)(ar + nxt);     pq1 = *(const float4*)(ar + nxt + 4);
            const float* wrow = W1 + (size_t)(nxt + bk) * H2 + nbase;
            pw0 = *(const float4*)(wrow + bc); pw1 = *(const float4*)(wrow + bc + 64);
        }
        #pragma unroll
        for (int kk = 0; kk < 16; ++kk) {
            const float4 aA = *(const float4*)&As[cur][kk][ty * 8];
            const float4 aB = *(const float4*)&As[cur][kk][ty * 8 + 4];
            const float4 b0 = *(const float4*)&Bs[cur][kk][tx * 4];
            const float4 b1v = *(const float4*)&Bs[cur][kk][tx * 4 + 64];
            v2f b00; b00[0] = b0.x;  b00[1] = b0.y;
            v2f b01; b01[0] = b0.z;  b01[1] = b0.w;
            v2f b10; b10[0] = b1v.x; b10[1] = b1v.y;
            v2f b11; b11[0] = b1v.z; b11[1] = b1v.w;
            const float arr[8] = {aA.x, aA.y, aA.z, aA.w, aB.x, aB.y, aB.z, aB.w};
            #pragma unroll
            for (int i = 0; i < 8; ++i) {
                v2f ai; ai[0] = arr[i]; ai[1] = arr[i];
                acc[i][0] = __builtin_elementwise_fma(ai, b00, acc[i][0]);
                acc[i][1] = __builtin_elementwise_fma(ai, b01, acc[i][1]);
                acc[i][2] = __builtin_elementwise_fma(ai, b10, acc[i][2]);
                acc[i][3] = __builtin_elementwise_fma(ai, b11, acc[i][3]);
            }
        }
        if (nxt < DIM) {
            const int nb = cur ^ 1;
            As[nb][sk + 0][srow] = __fadd_rn(__fmul_rn(ep, px0.x), pq0.x);
            As[nb][sk + 1][srow] = __fadd_rn(__fmul_rn(ep, px0.y), pq0.y);
            As[nb][sk + 2][srow] = __fadd_rn(__fmul_rn(ep, px0.z), pq0.z);
            As[nb][sk + 3][srow] = __fadd_rn(__fmul_rn(ep, px0.w), pq0.w);
            As[nb][sk + 4][srow] = __fadd_rn(__fmul_rn(ep, px1.x), pq1.x);
            As[nb][sk + 5][srow] = __fadd_rn(__fmul_rn(ep, px1.y), pq1.y);
            As[nb][sk + 6][srow] = __fadd_rn(__fmul_rn(ep, px1.z), pq1.z);
            As[nb][sk + 7][srow] = __fadd_rn(__fmul_rn(ep, px1.w), pq1.w);
            *(float4*)&Bs[nb][bk][bc]      = pw0;
            *(float4*)&Bs[nb][bk][bc + 64] = pw1;
            __syncthreads();
        }
        cur ^= 1;
    }
    const int gc = nbase + tx * 4;
    float bb[8], iv[8], gg[8], rr[8], ee[8];
    #pragma unroll
    for (int j = 0; j < 8; ++j) {
        int c = (j < 4) ? (gc + j) : (gc + 60 + j);
        bb[j] = b1[c];
        iv[j] = __fdiv_rn(1.0f, __fsqrt_rn(__fadd_rn(rv1[c], 1e-5f)));
        gg[j] = g1[c];
        rr[j] = rm1[c];
        ee[j] = be1[c];
    }
    #pragma unroll
    for (int i = 0; i < 8; ++i) {
        const int gr = mbase + ty * 8 + i;
        float cv[8] = {acc[i][0][0], acc[i][0][1], acc[i][1][0], acc[i][1][1],
                       acc[i][2][0], acc[i][2][1], acc[i][3][0], acc[i][3][1]};
        float r[8];
        #pragma unroll
        for (int j = 0; j < 8; ++j) {
            float t = __fadd_rn(cv[j], bb[j]);
            t = __fsub_rn(t, rr[j]); t = __fmul_rn(t, iv[j]);
            t = __fmul_rn(t, gg[j]); t = __fadd_rn(t, ee[j]);
            r[j] = fmaxf(t, 0.f);
        }
        float4 o0; o0.x = r[0]; o0.y = r[1]; o0.z = r[2]; o0.w = r[3];
        float4 o1; o1.x = r[4]; o1.y = r[5]; o1.z = r[6]; o1.w = r[7];
        *(float4*)(H1out + (size_t)gr * H2 + gc)      = o0;
        *(float4*)(H1out + (size_t)gr * H2 + gc + 64) = o1;
    }
}

// ---------------- GEMM2: 128x128 tile, BK=16, dbuf ping-pong, 1 barrier/iter ----------------
__global__ __launch_bounds__(256) void k_gemm2(const float* __restrict__ H1, const float* __restrict__ Ws2,
        const float* __restrict__ bs2, const float* __restrict__ gbn, const float* __restrict__ bbn,
        const float* __restrict__ rmbn, const float* __restrict__ rvbn, int l, float* __restrict__ Xout) {
    __shared__ float As[2][16][132];
    __shared__ float Bs[2][16][132];
    const float* W2 = Ws2 + (size_t)l * H2 * HID;
    const float* b2 = bs2 + l * HID;
    const float* g  = gbn + l * HID;
    const float* be = bbn + l * HID;
    const float* rm = rmbn + l * HID;
    const float* rv = rvbn + l * HID;
    int bid = blockIdx.x;
    int wg = (bid & 7) * 64 + (bid >> 3);
    const int mbase = wg * 128;
    const int tid = threadIdx.x;
    const int srow = tid >> 1;
    const int sk   = (tid & 1) * 8;
    const int bk   = tid >> 4;
    const int bc   = (tid & 15) * 4;
    const int ty = tid >> 4;
    const int tx = tid & 15;
    v2f acc[8][4] = {};
    const float* hr = H1 + (size_t)(mbase + srow) * H2 + sk;
    float4 ph0, ph1, pw0, pw1;
    ph0 = *(const float4*)(hr);     ph1 = *(const float4*)(hr + 4);
    {
        const float* wrow = W2 + (size_t)bk * HID;
        pw0 = *(const float4*)(wrow + bc); pw1 = *(const float4*)(wrow + bc + 64);
    }
    As[0][sk + 0][srow] = ph0.x;
    As[0][sk + 1][srow] = ph0.y;
    As[0][sk + 2][srow] = ph0.z;
    As[0][sk + 3][srow] = ph0.w;
    As[0][sk + 4][srow] = ph1.x;
    As[0][sk + 5][srow] = ph1.y;
    As[0][sk + 6][srow] = ph1.z;
    As[0][sk + 7][srow] = ph1.w;
    *(float4*)&Bs[0][bk][bc]      = pw0;
    *(float4*)&Bs[0][bk][bc + 64] = pw1;
    __syncthreads();
    int cur = 0;
    for (int kt = 0; kt < H2; kt += 16) {
        const int nxt = kt + 16;
        if (nxt < H2) {
            ph0 = *(const float4*)(hr + nxt);     ph1 = *(const float4*)(hr + nxt + 4);
            const float* wrow = W2 + (size_t)(nxt + bk) * HID;
            pw0 = *(const float4*)(wrow + bc); pw1 = *(const float4*)(wrow + bc + 64);
        }
        #pragma unroll
        for (int kk = 0; kk < 16; ++kk) {
            const float4 aA = *(const float4*)&As[cur][kk][ty * 8];
            const float4 aB = *(const float4*)&As[cur][kk][ty * 8 + 4];
            const float4 b0 = *(const float4*)&Bs[cur][kk][tx * 4];
            const float4 b1v = *(const float4*)&Bs[cur][kk][tx * 4 + 64];
            v2f b00; b00[0] = b0.x;  b00[1] = b0.y;
            v2f b01; b01[0] = b0.z;  b01[1] = b0.w;
            v2f b10; b10[0] = b1v.x; b10[1] = b1v.y;
            v2f b11; b11[0] = b1v.z; b11[1] = b1v.w;
            const float arr[8] = {aA.x, aA.y, aA.z, aA.w, aB.x, aB.y, aB.z, aB.w};
            #pragma unroll
            for (int i = 0; i < 8; ++i) {
                v2f ai; ai[0] = arr[i]; ai[1] = arr[i];
                acc[i][0] = __builtin_elementwise_fma(ai, b00, acc[i][0]);
                acc[i][1] = __builtin_elementwise_fma(ai, b01, acc[i][1]);
                acc[i][2] = __builtin_elementwise_fma(ai, b10, acc[i][2]);
                acc[i][3] = __builtin_elementwise_fma(ai, b11, acc[i][3]);
            }
        }
        if (nxt < H2) {
            const int nb = cur ^ 1;
            As[nb][sk + 0][srow] = ph0.x;
            As[nb][sk + 1][srow] = ph0.y;
            As[nb][sk + 2][srow] = ph0.z;
            As[nb][sk + 3][srow] = ph0.w;
            As[nb][sk + 4][srow] = ph1.x;
            As[nb][sk + 5][srow] = ph1.y;
            As[nb][sk + 6][srow] = ph1.z;
            As[nb][sk + 7][srow] = ph1.w;
            *(float4*)&Bs[nb][bk][bc]      = pw0;
            *(float4*)&Bs[nb][bk][bc + 64] = pw1;
            __syncthreads();
        }
        cur ^= 1;
    }
    const int gc = tx * 4;
    float bb[8], iv[8], gg[8], rr[8], ee[8];
    #pragma unroll
    for (int j = 0; j < 8; ++j) {
        int c = (j < 4) ? (gc + j) : (gc + 60 + j);
        bb[j] = b2[c];
        iv[j] = __fdiv_rn(1.0f, __fsqrt_rn(__fadd_rn(rv[c], 1e-5f)));
        gg[j] = g[c];
        rr[j] = rm[c];
        ee[j] = be[c];
    }
    #pragma unroll
    for (int i = 0; i < 8; ++i) {
        const int gr = mbase + ty * 8 + i;
        float cv[8] = {acc[i][0][0], acc[i][0][1], acc[i][1][0], acc[i][1][1],
                       acc[i][2][0], acc[i][2][1], acc[i][3][0], acc[i][3][1]};
        float r[8];
        #pragma unroll
        for (int j = 0; j < 8; ++j) {
            float t = __fadd_rn(cv[j], bb[j]);
            t = __fsub_rn(t, rr[j]); t = __fmul_rn(t, iv[j]);
            t = __fmul_rn(t, gg[j]); t = __fadd_rn(t, ee[j]);
            r[j] = fmaxf(t, 0.f);
        }
        float4 o0; o0.x = r[0]; o0.y = r[1]; o0.z = r[2]; o0.w = r[3];
        float4 o1; o1.x = r[4]; o1.y = r[5]; o1.z = r[6]; o1.w = r[7];
        *(float4*)(Xout + (size_t)gr * HID + gc)      = o0;
        *(float4*)(Xout + (size_t)gr * HID + gc + 64) = o1;
    }
}

// ---------------- fused agg + score (agg stays in regs; saves 67MB round-trip) ----------------
__global__ __launch_bounds__(256) void k_aggscore(const float* __restrict__ X,
        const int* __restrict__ row_start, const int* __restrict__ csr_src,
        const float* __restrict__ Wrel, const float* __restrict__ brel,
        const float* __restrict__ Wroot, float* __restrict__ S) {
    int bid = blockIdx.x;
    int wg = (bid & 7) * 1024 + (bid >> 3);
    int wave = threadIdx.x >> 6;
    int lane = threadIdx.x & 63;
    int half = lane >> 5;
    int l32 = lane & 31;
    int n = wg * 8 + wave * 2 + half;
    int beg = row_start[n], end = row_start[n + 1];
    const size_t co = (size_t)(l32 * 4);
    float a0 = 0.f, a1 = 0.f, a2 = 0.f, a3 = 0.f;
    int p = beg;
    for (; p + 8 <= end; p += 8) {
        int n0 = csr_src[p+0], n1 = csr_src[p+1], n2 = csr_src[p+2], n3 = csr_src[p+3];
        int n4 = csr_src[p+4], n5 = csr_src[p+5], n6 = csr_src[p+6], n7 = csr_src[p+7];
        float4 v0 = *(const float4*)(X + (size_t)n0 * DIM + co);
        float4 v1 = *(const float4*)(X + (size_t)n1 * DIM + co);
        float4 v2 = *(const float4*)(X + (size_t)n2 * DIM + co);
        float4 v3 = *(const float4*)(X + (size_t)n3 * DIM + co);
        float4 v4 = *(const float4*)(X + (size_t)n4 * DIM + co);
        float4 v5 = *(const float4*)(X + (size_t)n5 * DIM + co);
        float4 v6 = *(const float4*)(X + (size_t)n6 * DIM + co);
        float4 v7 = *(const float4*)(X + (size_t)n7 * DIM + co);
        a0 = __fadd_rn(a0, v0.x); a1 = __fadd_rn(a1, v0.y); a2 = __fadd_rn(a2, v0.z); a3 = __fadd_rn(a3, v0.w);
        a0 = __fadd_rn(a0, v1.x); a1 = __fadd_rn(a1, v1.y); a2 = __fadd_rn(a2, v1.z); a3 = __fadd_rn(a3, v1.w);
        a0 = __fadd_rn(a0, v2.x); a1 = __fadd_rn(a1, v2.y); a2 = __fadd_rn(a2, v2.z); a3 = __fadd_rn(a3, v2.w);
        a0 = __fadd_rn(a0, v3.x); a1 = __fadd_rn(a1, v3.y); a2 = __fadd_rn(a2, v3.z); a3 = __fadd_rn(a3, v3.w);
        a0 = __fadd_rn(a0, v4.x); a1 = __fadd_rn(a1, v4.y); a2 = __fadd_rn(a2, v4.z); a3 = __fadd_rn(a3, v4.w);
        a0 = __fadd_rn(a0, v5.x); a1 = __fadd_rn(a1, v5.y); a2 = __fadd_rn(a2, v5.z); a3 = __fadd_rn(a3, v5.w);
        a0 = __fadd_rn(a0, v6.x); a1 = __fadd_rn(a1, v6.y); a2 = __fadd_rn(a2, v6.z); a3 = __fadd_rn(a3, v6.w);
        a0 = __fadd_rn(a0, v7.x); a1 = __fadd_rn(a1, v7.y); a2 = __fadd_rn(a2, v7.z); a3 = __fadd_rn(a3, v7.w);
    }
    for (; p < end; ++p) {
        int nb = csr_src[p];
        float4 v = *(const float4*)(X + (size_t)nb * DIM + co);
        a0 = __fadd_rn(a0, v.x); a1 = __fadd_rn(a1, v.y); a2 = __fadd_rn(a2, v.z); a3 = __fadd_rn(a3, v.w);
    }
    // score: per-lane partial dots, then 32-lane tree reduce
    float4 xv  = *(const float4*)(X + (size_t)n * DIM + co);
    float4 wrv = *(const float4*)(Wrel + co);
    float4 wov = *(const float4*)(Wroot + co);
    float p1 = __fmul_rn(a0, wrv.x);
    p1 = __fmaf_rn(a1, wrv.y, p1);
    p1 = __fmaf_rn(a2, wrv.z, p1);
    p1 = __fmaf_rn(a3, wrv.w, p1);
    float p2 = __fmul_rn(xv.x, wov.x);
    p2 = __fmaf_rn(xv.y, wov.y, p2);
    p2 = __fmaf_rn(xv.z, wov.z, p2);
    p2 = __fmaf_rn(xv.w, wov.w, p2);
    #pragma unroll
    for (int off = 1; off <= 16; off <<= 1) {
        p1 += __shfl_xor(p1, off);
        p2 += __shfl_xor(p2, off);
    }
    if (l32 == 0) {
        float pp = __fadd_rn(__fadd_rn(p1, brel[0]), p2);
        const float PC = 7.90531110763549805f;
        float s;
        if (pp >= PC)       s = 1.0f;
        else if (pp <= -PC) s = -1.0f;
        else                s = (float)tanh((double)pp);
        S[n] = s;
    }
}

// ---------------- SAGPool top-K on f32 score (value desc, index asc) + pool ----------------
__global__ __launch_bounds__(512) void k_pool(const float* __restrict__ X, const float* __restrict__ S,
                                              float* __restrict__ EMB, double* __restrict__ EMB64) {
    __shared__ unsigned key[512];
    __shared__ double w[512];
    __shared__ double red[4][128];
    const int b = blockIdx.x, tid = threadIdx.x;
    float v = S[b * NNODE + tid];
    unsigned u = __float_as_uint(v);
    unsigned o = (u & 0x80000000u) ? ~u : (u | 0x80000000u);
    key[tid] = o;
    __syncthreads();
    int rank = 0;
    for (int j = 0; j < NNODE; ++j) {
        unsigned kj = key[j];
        rank += (int)((kj > o) || (kj == o && j < tid));
    }
    w[tid] = (rank < KSEL) ? (double)v : 0.0;
    __syncthreads();
    const int jgrp = tid >> 7;
    const int col = tid & 127;
    double acc = 0.0;
    for (int i = jgrp; i < NNODE; i += 4) {
        acc += (double)X[((size_t)b * NNODE + i) * HID + col] * w[i];
    }
    red[jgrp][col] = acc;
    __syncthreads();
    if (jgrp == 0) {
        double e = red[0][col] + red[1][col] + red[2][col] + red[3][col];
        EMB[b * HID + col] = (float)e;
        EMB64[b * HID + col] = e;
    }
}

// ---------------- head (f64) ----------------
__global__ __launch_bounds__(128) void k_head(const double* __restrict__ EMB64,
        const float* __restrict__ W1, const float* __restrict__ b1,
        const float* __restrict__ g, const float* __restrict__ be,
        const float* __restrict__ rm, const float* __restrict__ rv,
        const float* __restrict__ W2, const float* __restrict__ b2,
        float* __restrict__ LOGITS) {
    __shared__ double e[128];
    __shared__ double h[128];
    const int b = blockIdx.x, t = threadIdx.x;
    e[t] = EMB64[b * HID + t];
    __syncthreads();
    double acc = 0.0;
    for (int k = 0; k < HID; ++k) acc += e[k] * (double)W1[k * HID + t];
    acc += (double)b1[t];
    double inv = 1.0 / sqrt((double)rv[t] + 1e-5);
    acc = (acc - (double)rm[t]) * inv * (double)g[t] + (double)be[t];
    h[t] = fmax(acc, 0.0);
    __syncthreads();
    if (t < OUTC) {
        double a2 = (double)b2[t];
        for (int k = 0; k < HID; ++k) a2 += h[k] * (double)W2[k * OUTC + t];
        LOGITS[b * OUTC + t] = (float)a2;
    }
}

extern "C" void kernel_launch(void* const* d_in, const int* in_sizes, int n_in,
                              void* d_out, int out_size, void* d_ws, size_t ws_size,
                              hipStream_t stream) {
    const float* x     = (const float*)d_in[0];
    const int*   edge  = (const int*)d_in[1];
    const int*   src   = edge;
    const int*   dst   = edge + EDGES;
    const float* epss  = (const float*)d_in[3];
    const float* Ws1   = (const float*)d_in[4];
    const float* bs1   = (const float*)d_in[5];
    const float* g1s   = (const float*)d_in[6];
    const float* be1s  = (const float*)d_in[7];
    const float* rm1s  = (const float*)d_in[8];
    const float* rv1s  = (const float*)d_in[9];
    const float* Ws2   = (const float*)d_in[10];
    const float* bs2   = (const float*)d_in[11];
    const float* gbn   = (const float*)d_in[12];
    const float* bbn   = (const float*)d_in[13];
    const float* rmbn  = (const float*)d_in[14];
    const float* rvbn  = (const float*)d_in[15];
    const float* Wrel  = (const float*)d_in[16];
    const float* brel  = (const float*)d_in[17];
    const float* Wroot = (const float*)d_in[18];
    const float* W_lin1= (const float*)d_in[19];
    const float* b_lin1= (const float*)d_in[20];
    const float* g_h   = (const float*)d_in[21];
    const float* be_h  = (const float*)d_in[22];
    const float* rm_h  = (const float*)d_in[23];
    const float* rv_h  = (const float*)d_in[24];
    const float* W_lin2= (const float*)d_in[25];
    const float* b_lin2= (const float*)d_in[26];

    char* ws = (char*)d_ws;
    float*  x_cur    = (float*) (ws);                    // 32 MB
    float*  agg      = (float*) (ws + 33554432);         // 32 MB
    float*  h1       = (float*) (ws + 67108864);         // 64 MB
    float*  s32      = (float*) (ws + 134217728);        // 256 KB
    double* emb64    = (double*)(ws + 134479872);        // 128 KB
    int*    row_start= (int*)   (ws + 134610944);        // 256 KB + 4
    int*    cursor   = (int*)   (ws + 134877184);        // 256 KB
    int*    counts   = (int*)   (ws + 135139328);        // 256 KB
    int*    csr     = (int*)    (ws + 135401472);        // 4 MB

    float* emb    = (float*)d_out;
    float* logits = (float*)d_out + BGRAPH * HID;

    // ---- CSR (by dst): counts -> scan -> fill(eids) -> LDS row sort (edge order) ----
    hipMemsetAsync(counts, 0, NT_ * sizeof(int), stream);
    k_count<<<EDGES / 256, 256, 0, stream>>>(dst, counts);
    k_scan<<<1, 1024, 0, stream>>>(counts, row_start, cursor);
    k_fill<<<EDGES / 256, 256, 0, stream>>>(dst, cursor, csr);
    k_sortrows<<<NT_ / 256, 256, 0, stream>>>(src, row_start, csr);

    // ---- layer 0 ----
    k_agg<<<NT_ / 8, 256, 0, stream>>>(x, row_start, csr, agg);
    k_gemm1<<<1024, 256, 0, stream>>>(x, agg, epss, Ws1, bs1, g1s, be1s, rm1s, rv1s, 0, h1);
    k_gemm2<<<512, 256, 0, stream>>>(h1, Ws2, bs2, gbn, bbn, rmbn, rvbn, 0, x_cur);
    // ---- layer 1 ----
    k_agg<<<NT_ / 8, 256, 0, stream>>>(x_cur, row_start, csr, agg);
    k_gemm1<<<1024, 256, 0, stream>>>(x_cur, agg, epss, Ws1, bs1, g1s, be1s, rm1s, rv1s, 1, h1);
    k_gemm2<<<512, 256, 0, stream>>>(h1, Ws2, bs2, gbn, bbn, rmbn, rvbn, 1, x_cur);
    // ---- fused agg+score, pool, head ----
    k_aggscore<<<NT_ / 8, 256, 0, stream>>>(x_cur, row_start, csr, Wrel, brel, Wroot, s32);
    k_pool<<<BGRAPH, 512, 0, stream>>>(x_cur, s32, emb, emb64);
    k_head<<<BGRAPH, 128, 0, stream>>>(emb64, W_lin1, b_lin1, g_h, be_h, rm_h, rv_h, W_lin2, b_lin2, logits);
}